// Round 5
// baseline (179.366 us; speedup 1.0000x reference)
//
#include <hip/hip_runtime.h>

// Modulated deformable conv, fp32 in/out. B=4, CIN=COUT=256, H=W=64, KS=3, PAD=1.
// R17: evict offset-conv from k_all.
//  R16 post-mortem: scheduler re-sinks loads regardless of vgpr budget; source-
//  level ILP fights are neutral. Structural fix instead: phase1 paid the full
//  latency skeleton (stage+barrier) for 9/18 taps at 1/8 MFMA utilization.
//  - NEW k_off: barrier-free, LDS-free register gather-GEMM for the offset conv
//    (2xuint4 gather + v_perm pack per K-step directly from xpair), bitwise-
//    identical accumulation order to old phase1; computes phase-2 params and
//    stores pwt/pidx to ws (indexed by sid -> k_all loads coalesced).
//  - k_all MODE2: params from ws, ONLY the 9-tap sampling+GEMM loop (R15 body).
//  - Fallbacks: MODE1 = R15 full pair path (ws too small for params);
//    MODE0 = direct-fp32 path.
// ws: [xpairT 16MB][wfrag 1.33MB][pwt 2.36MB][pidx 1.18MB] = 21,643,264 B.

#define WOFF_FRAG_OFF 589824
#define XPAIR_BYTES   16777216ull
#define WFRAG_BYTES   1327104ull
#define PWT_BYTES     2359296ull
#define PIDX_BYTES    1179648ull

typedef unsigned short ushort_t;
typedef unsigned int   uint_t;

using short8 = __attribute__((ext_vector_type(8))) short;
using f32x4  = __attribute__((ext_vector_type(4))) float;
using uint4v = __attribute__((ext_vector_type(4))) uint_t;

struct __attribute__((packed, aligned(4))) pairf { float x, y; };

__device__ inline ushort_t f2bf(float v) {
    unsigned u = __float_as_uint(v);
    unsigned r = u + 0x7fffu + ((u >> 16) & 1u);   // RNE (inputs finite)
    return (ushort_t)(r >> 16);
}
__device__ inline float bflo(uint_t u) { return __uint_as_float(u << 16); }
__device__ inline float bfhi(uint_t u) { return __uint_as_float(u & 0xffff0000u); }

__device__ inline uint_t pk1(uint_t u0, uint_t u1, bool v) {
    return v ? ((u0 & 0xffffu) | (u1 << 16)) : 0u;
}
__device__ inline uint_t interp2(uint_t a0, uint_t a1, uint_t b0, uint_t b1, float4 wt) {
    const float v0 = (bflo(a0) * wt.x + bfhi(a0) * wt.y) * wt.z
                   + (bflo(a1) * wt.x + bfhi(a1) * wt.y) * wt.w;
    const float v1 = (bflo(b0) * wt.x + bfhi(b0) * wt.y) * wt.z
                   + (bflo(b1) * wt.x + bfhi(b1) * wt.y) * wt.w;
    return (uint_t)f2bf(v0) | ((uint_t)f2bf(v1) << 16);
}

// LDS-visibility barrier WITHOUT vmcnt drain: in-flight global loads survive.
#define BAR() do {                                              \
    asm volatile("s_waitcnt lgkmcnt(0)" ::: "memory");          \
    __builtin_amdgcn_s_barrier();                               \
    asm volatile("" ::: "memory");                              \
} while (0)

// k_pre: blocks [0,XB): xpairT tile-transpose; [XB,XB+144): w_conv frags;
// [XB+144,XB+162): w_off frags. All global stores coalesced 16B. 512 thr.
__global__ __launch_bounds__(512) void k_pre(
    const float* __restrict__ x,
    const float* __restrict__ w_conv,
    const float* __restrict__ w_off,
    ushort_t* __restrict__ wfrag,
    uint_t* __restrict__ xpair,
    int XB)
{
    __shared__ __align__(16) float xt[256 * 32];   // [cin][i^swz] fp32 tile, 32 KB
    __shared__ float xcol[256];                    // 33rd column (i==32)
    const int bid = blockIdx.x;
    const int t = threadIdx.x;
    if (bid < XB) {
        const int b = bid >> 7;
        const int idx0 = (bid & 127) << 5;           // 32 idx rows per block
        const float* xb = x + (b << 20);
#pragma unroll
        for (int r = 0; r < 4; ++r) {
            const int f = r * 512 + t;               // float4 id, 0..2047
            const int cin = f >> 3, k = f & 7;
            const float4 v = *(const float4*)&xb[(cin << 12) + idx0 + (k << 2)];
            const int swz = ((cin >> 2) & 7) << 2;   // XOR on i bits [2:4]
            *(float4*)&xt[(cin << 5) + ((k << 2) ^ swz)] = v;
        }
        if (t < 256)
            xcol[t] = ((idx0 & 63) == 0) ? xb[(t << 12) + idx0 + 32] : 0.f;
        __syncthreads();
        uint_t* op = xpair + (((b << 12) + idx0) << 8);
#pragma unroll
        for (int r = 0; r < 4; ++r) {
            const int g = r * 512 + t;               // uint4 id, 0..2047
            const int il = g >> 6, c4 = (g & 63) << 2;
            uint_t o[4];
#pragma unroll
            for (int j = 0; j < 4; ++j) {
                const int c = c4 + j;
                const int swz = ((c >> 2) & 7) << 2;
                const float lo = xt[(c << 5) + (il ^ swz)];
                const float hi = (il < 31) ? xt[(c << 5) + ((il + 1) ^ swz)]
                                           : xcol[c];
                o[j] = (uint_t)f2bf(lo) | ((uint_t)f2bf(hi) << 16);
            }
            *(uint4*)(op + (il << 8) + c4) = make_uint4(o[0], o[1], o[2], o[3]);
        }
        return;
    }
    const int wb = bid - XB;
    if (wb < 144) {                                   // w_conv fragment rows
        const int i8 = wb * 512 + t;                  // 0..73727
        const int lane = i8 & 63;
        const int nt = (i8 >> 6) & 15;
        const int kt = i8 >> 10;                      // 0..71
        const int n = nt * 16 + (lane & 15);
        const int k0 = kt * 32 + ((lane >> 4) << 3);
        ushort_t v[8];
#pragma unroll
        for (int j = 0; j < 8; ++j) {
            const int kn = k0 + j;                    // tap-outer: kn = tap*256+cin
            const int cin = kn & 255, tap = kn >> 8;
            v[j] = f2bf(w_conv[n * 2304 + cin * 9 + tap]);
        }
        uint4 o;
        o.x = (uint_t)v[0] | ((uint_t)v[1] << 16);
        o.y = (uint_t)v[2] | ((uint_t)v[3] << 16);
        o.z = (uint_t)v[4] | ((uint_t)v[5] << 16);
        o.w = (uint_t)v[6] | ((uint_t)v[7] << 16);
        *(uint4*)(wfrag + (size_t)i8 * 8) = o;
    } else {                                          // w_off fragment rows (+pad)
        const int i8 = (wb - 144) * 512 + t;          // 0..9215
        const int lane = i8 & 63;
        const int nt = (i8 >> 6) & 1;
        const int kt = i8 >> 7;                       // 0..71
        const int n = nt * 16 + (lane & 15);
        const int k0 = kt * 32 + ((lane >> 4) << 3);
        ushort_t v[8];
#pragma unroll
        for (int j = 0; j < 8; ++j) {
            const int kn = k0 + j;
            const int cin = kn & 255, tap = kn >> 8;
            v[j] = (n < 27) ? f2bf(w_off[n * 2304 + cin * 9 + tap]) : (ushort_t)0;
        }
        uint4 o;
        o.x = (uint_t)v[0] | ((uint_t)v[1] << 16);
        o.y = (uint_t)v[2] | ((uint_t)v[3] << 16);
        o.z = (uint_t)v[4] | ((uint_t)v[5] << 16);
        o.w = (uint_t)v[6] | ((uint_t)v[7] << 16);
        *(uint4*)(wfrag + WOFF_FRAG_OFF + (size_t)i8 * 8) = o;
    }
}

// k_off: offset conv + sampling params. 512 blocks x 256 thr (4 waves).
// Barrier-free, LDS-free gather-GEMM: wave wv = (m_sub, nt); lane (px, quad)
// gathers its A-frag (8 cins' lo halves) straight from xpair into registers.
// Accumulation order == old k_all phase1 (tap outer, k2 inner) -> bitwise same.
__global__ __launch_bounds__(256) void k_off(
    const uint_t* __restrict__ xpair,
    const float* __restrict__ b_off,
    const ushort_t* __restrict__ wfrag,
    float4* __restrict__ pwt_g,
    int2* __restrict__ pidx_g)
{
    __shared__ float om_s[32 * 32];                  // [cout][px]
    const int bid = blockIdx.x;
    const int sid = ((bid & 7) << 6) | (bid >> 3);   // same mapping as k_all
    const int m0  = sid << 5;
    const int b   = m0 >> 12;
    const int h   = (m0 >> 6) & 63;
    const int wbase = m0 & 63;
    const int tid = threadIdx.x;
    const int lane = tid & 63;
    const int wv = tid >> 6;                          // 0..3
    const int m_sub = wv >> 1;                        // 0..1: px half
    const int nt = wv & 1;                            // 0..1: cout tile
    const int quad = lane >> 4;
    const int pxl = (m_sub << 4) + (lane & 15);       // A-row: local px 0..31
    const uint_t* xq = xpair + (b << 20);
    const ushort_t* woffb = wfrag + WOFF_FRAG_OFF;

    f32x4 acc = {0.f, 0.f, 0.f, 0.f};
    for (int tap = 0; tap < 9; ++tap) {
        const int ky = (tap * 11) >> 5, kx = tap - ky * 3;
        const int yy = h + ky - 1;
        const int xx = wbase + pxl + kx - 1;
        const bool v = ((unsigned)yy < 64u) & ((unsigned)xx < 64u);
        const int idx = v ? (yy << 6) + xx : 0;
        const uint_t mAll = v ? 0xffffffffu : 0u;
        const uint_t* pr = xq + (idx << 8);
#pragma unroll
        for (int k2 = 0; k2 < 8; ++k2) {
            const int cin0 = k2 * 32 + (quad << 3);
            const uint4v u0 = *(const uint4v*)(pr + cin0);
            const uint4v u1 = *(const uint4v*)(pr + cin0 + 4);
            uint4v pk;
            pk.x = __builtin_amdgcn_perm(u0.y, u0.x, 0x05040100u) & mAll;
            pk.y = __builtin_amdgcn_perm(u0.w, u0.z, 0x05040100u) & mAll;
            pk.z = __builtin_amdgcn_perm(u1.y, u1.x, 0x05040100u) & mAll;
            pk.w = __builtin_amdgcn_perm(u1.w, u1.z, 0x05040100u) & mAll;
            const short8 a = __builtin_bit_cast(short8, pk);
            const short8 bf = *(const short8*)(woffb + (((tap * 8 + k2) * 2 + nt) * 64 + lane) * 8);
            acc = __builtin_amdgcn_mfma_f32_16x16x32_bf16(a, bf, acc, 0, 0, 0);
        }
    }
    // C/D: col=lane&15 (cout-in-tile), rows = quad*4+reg (px-in-mtile)
    {
        const int c = (nt << 4) + (lane & 15);
        *(f32x4*)&om_s[c * 32 + (m_sub << 4) + (quad << 2)] = acc;
    }
    __syncthreads();
    // phase-2 param math (identical to old k_all phase 2), 288 entries / 256 thr
    for (int t = tid; t < 288; t += 256) {
        const int p2 = t & 31, tap = t >> 5;
        const int ky = (tap * 11) >> 5, kx = tap - ky * 3;
        const float dyv = om_s[(2 * tap) * 32 + p2] + b_off[2 * tap];
        const float dxv = om_s[(2 * tap + 1) * 32 + p2] + b_off[2 * tap + 1];
        const float mo  = om_s[(18 + tap) * 32 + p2] + b_off[18 + tap];
        const float mv  = 1.f / (1.f + expf(-mo));
        const float py  = dyv + (float)(h - 1 + ky);
        const float pxf = dxv + (float)(wbase + p2 - 1 + kx);
        const float y0f = floorf(py), x0f = floorf(pxf);
        const float wy = py - y0f,    wx = pxf - x0f;
        const float vy0 = (y0f >=  0.f && y0f <= 63.f) ? 1.f : 0.f;
        const float vy1 = (y0f >= -1.f && y0f <= 62.f) ? 1.f : 0.f;
        const int ry0 = (int)fminf(fmaxf(y0f, 0.f), 63.f);
        const int ry1 = (int)fminf(fmaxf(y0f + 1.f, 0.f), 63.f);
        const float rw0 = (1.f - wy) * vy0 * mv;
        const float rw1 = wy * vy1 * mv;
        const bool in01 = (x0f >= 0.f && x0f <= 62.f);
        const float wa = in01 ? (1.f - wx) : ((x0f == -1.f) ? wx : 0.f);
        const float wb = in01 ? wx : ((x0f == 63.f) ? (1.f - wx) : 0.f);
        const int bx = (int)fminf(fmaxf(x0f, 0.f), 62.f);
        pwt_g[sid * 288 + t]  = make_float4(wa, wb, rw0, rw1);
        pidx_g[sid * 288 + t] = make_int2(ry0 * 64 + bx, ry1 * 64 + bx);
    }
}

// ---- prefetch macros: explicit named uint4 scalars (NO arrays -> SROA-safe) ----
#define ISSUE1(tap) do {                                                     \
    const int ky_ = ((tap) * 11) >> 5, kx_ = (tap) - ky_ * 3;                \
    const int yy_ = h + ky_ - 1;                                             \
    const int xx_ = wbase + px + kx_ - 1;                                    \
    s1v = ((unsigned)yy_ < 64u) & ((unsigned)xx_ < 64u);                     \
    const int idx_ = s1v ? (yy_ << 6) + xx_ : 0;                             \
    const uint_t* p_ = xq + (idx_ << 8) + (slot << 4);                       \
    s1a = *(const uint4*)(p_);      s1b = *(const uint4*)(p_ + 4);           \
    s1c = *(const uint4*)(p_ + 8);  s1d = *(const uint4*)(p_ + 12);          \
} while (0)

#define WRITE1(bufi) do {                                                    \
    uint_t* dst_ = (uint_t*)&As[bufi][0] + px * 132 + slot * 8;              \
    *(uint4*)dst_ = make_uint4(pk1(s1a.x, s1a.y, s1v), pk1(s1a.z, s1a.w, s1v), \
                               pk1(s1b.x, s1b.y, s1v), pk1(s1b.z, s1b.w, s1v)); \
    *(uint4*)(dst_ + 4) = make_uint4(pk1(s1c.x, s1c.y, s1v), pk1(s1c.z, s1c.w, s1v), \
                                     pk1(s1d.x, s1d.y, s1v), pk1(s1d.z, s1d.w, s1v)); \
} while (0)

#define ISSUE3(tap) do {                                                     \
    const int2 ii_ = pidx[(tap) * 32 + px];                                  \
    const uint_t* p0_ = xq + (ii_.x << 8) + (slot << 4);                     \
    const uint_t* p1_ = xq + (ii_.y << 8) + (slot << 4);                     \
    r0a = *(const uint4*)(p0_);      r0b = *(const uint4*)(p0_ + 4);         \
    r0c = *(const uint4*)(p0_ + 8);  r0d = *(const uint4*)(p0_ + 12);        \
    r1a = *(const uint4*)(p1_);      r1b = *(const uint4*)(p1_ + 4);         \
    r1c = *(const uint4*)(p1_ + 8);  r1d = *(const uint4*)(p1_ + 12);        \
} while (0)

#define WRITE3(tap, bufi) do {                                               \
    const float4 wt_ = pwt[(tap) * 32 + px];                                 \
    uint_t* dst_ = (uint_t*)&As[bufi][0] + px * 132 + slot * 8;              \
    *(uint4*)dst_ = make_uint4(                                              \
        interp2(r0a.x, r1a.x, r0a.y, r1a.y, wt_),                            \
        interp2(r0a.z, r1a.z, r0a.w, r1a.w, wt_),                            \
        interp2(r0b.x, r1b.x, r0b.y, r1b.y, wt_),                            \
        interp2(r0b.z, r1b.z, r0b.w, r1b.w, wt_));                           \
    *(uint4*)(dst_ + 4) = make_uint4(                                        \
        interp2(r0c.x, r1c.x, r0c.y, r1c.y, wt_),                            \
        interp2(r0c.z, r1c.z, r0c.w, r1c.w, wt_),                            \
        interp2(r0d.x, r1d.x, r0d.y, r1d.y, wt_),                            \
        interp2(r0d.z, r1d.z, r0d.w, r1d.w, wt_));                           \
} while (0)

// ---- k_all: block = 32 px x 256 couts, 512 thr = 8 waves, grid 512 ----
// MODE 2: params precomputed by k_off; phase 3 only. MODE 1: full pair path.
// MODE 0: direct-fp32 fallback.
template<int MODE>
__global__ __launch_bounds__(512, 4) void k_all(
    const float* __restrict__ x,
    const uint_t* __restrict__ xpair,
    const float* __restrict__ b_off,
    const ushort_t* __restrict__ wfrag,
    float* __restrict__ out,
    const float4* __restrict__ pwt_g,
    const int2* __restrict__ pidx_g)
{
    __shared__ short As[2][32 * 264];                // 33,792 B; px stride 264 shorts
    __shared__ __align__(16) float4 pwt[9 * 32];
    __shared__ __align__(16) int2   pidx[9 * 32];
    float* om_s = (float*)&As[0][0];                 // 32c x 32px fp32 alias

    const int bid = blockIdx.x;
    const int sid = ((bid & 7) << 6) | (bid >> 3);   // XCD-contiguous bands
    const int m0  = sid << 5;
    const int b   = m0 >> 12;
    const int h   = (m0 >> 6) & 63;
    const int wbase = m0 & 63;                        // 0 or 32
    const int tid  = threadIdx.x;
    const int lane = tid & 63;
    const int wv   = tid >> 6;                        // 0..7
    const int quad = lane >> 4;
    const int px   = tid & 31;                        // staging pixel
    const int slot = tid >> 5;                        // 0..15: 16 cins each

    const float*  xb = x + (b << 20);
    const uint_t* xq = xpair + (b << 20);
    const ushort_t* woffb = wfrag + WOFF_FRAG_OFF;

    if constexpr (MODE == 2) {
        // params from k_off: coalesced 16B/8B loads into LDS
        if (tid < 288) {
            pwt[tid]  = pwt_g[sid * 288 + tid];
            pidx[tid] = pidx_g[sid * 288 + tid];
        }
        __syncthreads();
    } else {
        // ================= phase 1: offset conv via MFMA =================
        const int m_w = wv & 1, nt_w = (wv >> 1) & 1;
        f32x4 om_acc = {0.f, 0.f, 0.f, 0.f};

        if constexpr (MODE == 1) {
            uint4 s1a, s1b, s1c, s1d; bool s1v = false;
            ISSUE1(0);
            WRITE1(0);
            ISSUE1(1);
            BAR();
            for (int tap = 0; tap < 9; ++tap) {
                if (tap < 8) WRITE1((tap + 1) & 1);
                if (tap < 7) ISSUE1(tap + 2);
                if (wv < 4) {
                    const short* cur = &As[tap & 1][0];
#pragma unroll
                    for (int k2 = 0; k2 < 8; ++k2) {
                        const int ktg = tap * 8 + k2;
                        const short8 a = *(const short8*)&cur[((m_w << 4) + (lane & 15)) * 264 + k2 * 32 + quad * 8];
                        const short8 bf = *(const short8*)(woffb + ((ktg * 2 + nt_w) * 64 + lane) * 8);
                        om_acc = __builtin_amdgcn_mfma_f32_16x16x32_bf16(a, bf, om_acc, 0, 0, 0);
                    }
                }
                BAR();
            }
        } else {
            auto stage1 = [&](int tap, int bufi) {
                const int ky = (tap * 11) >> 5, kx = tap - ky * 3;
                const int yy = h + ky - 1;
                const int xx = wbase + px + kx - 1;
                const bool v = ((unsigned)yy < 64u) & ((unsigned)xx < 64u);
                const int idx = v ? (yy << 6) + xx : 0;
                uint_t lo16[16];
#pragma unroll
                for (int c = 0; c < 16; ++c) {
                    const int cin = (slot << 4) + c;
                    const float t0 = xb[(cin << 12) + idx];
                    lo16[c] = v ? (uint_t)f2bf(t0) : 0u;
                }
                uint_t o[8];
#pragma unroll
                for (int k = 0; k < 8; ++k) o[k] = lo16[2 * k] | (lo16[2 * k + 1] << 16);
                uint_t* dst = (uint_t*)&As[bufi][0] + px * 132 + slot * 8;
                *(uint4*)dst       = make_uint4(o[0], o[1], o[2], o[3]);
                *(uint4*)(dst + 4) = make_uint4(o[4], o[5], o[6], o[7]);
            };
            auto mfma1 = [&](int tap) {
                if (wv < 4) {
                    const short* cur = &As[tap & 1][0];
#pragma unroll
                    for (int k2 = 0; k2 < 8; ++k2) {
                        const int ktg = tap * 8 + k2;
                        const short8 a = *(const short8*)&cur[((m_w << 4) + (lane & 15)) * 264 + k2 * 32 + quad * 8];
                        const short8 bf = *(const short8*)(woffb + ((ktg * 2 + nt_w) * 64 + lane) * 8);
                        om_acc = __builtin_amdgcn_mfma_f32_16x16x32_bf16(a, bf, om_acc, 0, 0, 0);
                    }
                }
            };
            stage1(0, 0);
            __syncthreads();
            for (int tap = 0; tap < 9; ++tap) {
                if (tap < 8) stage1(tap + 1, (tap + 1) & 1);
                mfma1(tap);
                __syncthreads();
            }
        }

        if (wv < 4) {
            const int c = (nt_w << 4) + (lane & 15);
            *(f32x4*)&om_s[c * 32 + (m_w << 4) + (quad << 2)] = om_acc;
        }
        __syncthreads();

        // ================= phase 2: per-(tap,px) pair-gather params =============
        if (tid < 288) {
            const int p2 = tid & 31, tap = tid >> 5;
            const int ky = (tap * 11) >> 5, kx = tap - ky * 3;
            const float dyv = om_s[(2 * tap) * 32 + p2] + b_off[2 * tap];
            const float dxv = om_s[(2 * tap + 1) * 32 + p2] + b_off[2 * tap + 1];
            const float mo  = om_s[(18 + tap) * 32 + p2] + b_off[18 + tap];
            const float mv  = 1.f / (1.f + expf(-mo));
            const float py  = dyv + (float)(h - 1 + ky);
            const float pxf = dxv + (float)(wbase + p2 - 1 + kx);
            const float y0f = floorf(py), x0f = floorf(pxf);
            const float wy = py - y0f,    wx = pxf - x0f;
            const float vy0 = (y0f >=  0.f && y0f <= 63.f) ? 1.f : 0.f;
            const float vy1 = (y0f >= -1.f && y0f <= 62.f) ? 1.f : 0.f;
            const int ry0 = (int)fminf(fmaxf(y0f, 0.f), 63.f);
            const int ry1 = (int)fminf(fmaxf(y0f + 1.f, 0.f), 63.f);
            const float rw0 = (1.f - wy) * vy0 * mv;
            const float rw1 = wy * vy1 * mv;
            const bool in01 = (x0f >= 0.f && x0f <= 62.f);
            const float wa = in01 ? (1.f - wx) : ((x0f == -1.f) ? wx : 0.f);
            const float wb = in01 ? wx : ((x0f == 63.f) ? (1.f - wx) : 0.f);
            const int bx = (int)fminf(fmaxf(x0f, 0.f), 62.f);
            pwt[tid]  = make_float4(wa, wb, rw0, rw1);
            pidx[tid] = make_int2(ry0 * 64 + bx, ry1 * 64 + bx);
        }
        __syncthreads();
    }

    // ================= phase 3: sampling + main GEMM =================
    f32x4 acc00 = {0.f, 0.f, 0.f, 0.f}, acc01 = {0.f, 0.f, 0.f, 0.f};
    f32x4 acc10 = {0.f, 0.f, 0.f, 0.f}, acc11 = {0.f, 0.f, 0.f, 0.f};

    const int nt_base = wv << 1;                      // wave's couts: wv*32..+31

    if constexpr (MODE >= 1) {
        uint4 r0a, r0b, r0c, r0d, r1a, r1b, r1c, r1d;
        ISSUE3(0);
        WRITE3(0, 0);
        ISSUE3(1);
        BAR();
        for (int tap = 0; tap < 9; ++tap) {
            if (tap < 8) WRITE3(tap + 1, (tap + 1) & 1);
            if (tap < 7) ISSUE3(tap + 2);            // in flight across MFMA+BAR
            const short* cur = &As[tap & 1][0];
#pragma unroll
            for (int k2 = 0; k2 < 8; ++k2) {
                const int ktg = tap * 8 + k2;
                const short8 a0v = *(const short8*)&cur[(lane & 15) * 264 + k2 * 32 + quad * 8];
                const short8 a1v = *(const short8*)&cur[((lane & 15) + 16) * 264 + k2 * 32 + quad * 8];
                const short8 bf0 = *(const short8*)(wfrag + ((ktg * 16 + nt_base) * 64 + lane) * 8);
                const short8 bf1 = *(const short8*)(wfrag + ((ktg * 16 + nt_base + 1) * 64 + lane) * 8);
                acc00 = __builtin_amdgcn_mfma_f32_16x16x32_bf16(a0v, bf0, acc00, 0, 0, 0);
                acc01 = __builtin_amdgcn_mfma_f32_16x16x32_bf16(a0v, bf1, acc01, 0, 0, 0);
                acc10 = __builtin_amdgcn_mfma_f32_16x16x32_bf16(a1v, bf0, acc10, 0, 0, 0);
                acc11 = __builtin_amdgcn_mfma_f32_16x16x32_bf16(a1v, bf1, acc11, 0, 0, 0);
            }
            BAR();
        }
    } else {
        auto stage3 = [&](int tap, int bufi) {
            const float4 wt = pwt[tap * 32 + px];
            const int2   ii = pidx[tap * 32 + px];
            uint_t o[8];
#pragma unroll
            for (int k = 0; k < 8; ++k) {
                ushort_t s[2];
#pragma unroll
                for (int u = 0; u < 2; ++u) {
                    const int cin = (slot << 4) + 2 * k + u;
                    const pairf pa = *(const pairf*)(xb + (cin << 12) + ii.x);
                    const pairf pb = *(const pairf*)(xb + (cin << 12) + ii.y);
                    const float v = (pa.x * wt.x + pa.y * wt.y) * wt.z
                                  + (pb.x * wt.x + pb.y * wt.y) * wt.w;
                    s[u] = f2bf(v);
                }
                o[k] = (uint_t)s[0] | ((uint_t)s[1] << 16);
            }
            uint_t* dst = (uint_t*)&As[bufi][0] + px * 132 + slot * 8;
            *(uint4*)dst       = make_uint4(o[0], o[1], o[2], o[3]);
            *(uint4*)(dst + 4) = make_uint4(o[4], o[5], o[6], o[7]);
        };
        auto mfma3 = [&](int tap) {
            const short* cur = &As[tap & 1][0];
#pragma unroll
            for (int k2 = 0; k2 < 8; ++k2) {
                const int ktg = tap * 8 + k2;
                const short8 a0v = *(const short8*)&cur[(lane & 15) * 264 + k2 * 32 + quad * 8];
                const short8 a1v = *(const short8*)&cur[((lane & 15) + 16) * 264 + k2 * 32 + quad * 8];
                const short8 bf0 = *(const short8*)(wfrag + ((ktg * 16 + nt_base) * 64 + lane) * 8);
                const short8 bf1 = *(const short8*)(wfrag + ((ktg * 16 + nt_base + 1) * 64 + lane) * 8);
                acc00 = __builtin_amdgcn_mfma_f32_16x16x32_bf16(a0v, bf0, acc00, 0, 0, 0);
                acc01 = __builtin_amdgcn_mfma_f32_16x16x32_bf16(a0v, bf1, acc01, 0, 0, 0);
                acc10 = __builtin_amdgcn_mfma_f32_16x16x32_bf16(a1v, bf0, acc10, 0, 0, 0);
                acc11 = __builtin_amdgcn_mfma_f32_16x16x32_bf16(a1v, bf1, acc11, 0, 0, 0);
            }
        };
        stage3(0, 0);
        __syncthreads();
        for (int tap = 0; tap < 9; ++tap) {
            if (tap < 8) stage3(tap + 1, (tap + 1) & 1);
            mfma3(tap);
            __syncthreads();
        }
    }

    // epilogue: w = wbase + m*16 + quad*4 + reg; cout n = wv*32 + nn*16 + (lane&15)
    {
        const int w0 = wbase + (quad << 2);
        const int w1 = wbase + 16 + (quad << 2);
        const int n0 = (wv << 5) + (lane & 15);
        const int n1 = (wv << 5) + 16 + (lane & 15);
        *(f32x4*)(out + (((size_t)((b << 8) + n0)) << 12) + (h << 6) + w0) = acc00;
        *(f32x4*)(out + (((size_t)((b << 8) + n1)) << 12) + (h << 6) + w0) = acc01;
        *(f32x4*)(out + (((size_t)((b << 8) + n0)) << 12) + (h << 6) + w1) = acc10;
        *(f32x4*)(out + (((size_t)((b << 8) + n1)) << 12) + (h << 6) + w1) = acc11;
    }
}

extern "C" void kernel_launch(void* const* d_in, const int* in_sizes, int n_in,
                              void* d_out, int out_size, void* d_ws, size_t ws_size,
                              hipStream_t stream) {
    const float* x      = (const float*)d_in[0];
    const float* w_off  = (const float*)d_in[1];
    const float* b_off  = (const float*)d_in[2];
    const float* w_conv = (const float*)d_in[3];
    float* out = (float*)d_out;

    const size_t need1 = XPAIR_BYTES + WFRAG_BYTES;                          // 18,104,320
    const size_t need2 = need1 + PWT_BYTES + PIDX_BYTES;                     // 21,643,264
    const int mode = (ws_size >= need2) ? 2 : ((ws_size >= need1) ? 1 : 0);

    uint_t*   xpair = (uint_t*)d_ws;
    ushort_t* wfrag = (mode >= 1) ? (ushort_t*)((char*)d_ws + XPAIR_BYTES)
                                  : (ushort_t*)d_ws;
    float4* pwt_g = (float4*)((char*)d_ws + XPAIR_BYTES + WFRAG_BYTES);
    int2*   pidx_g = (int2*)((char*)d_ws + XPAIR_BYTES + WFRAG_BYTES + PWT_BYTES);
    const int XB = (mode >= 1) ? 512 : 0;

    hipLaunchKernelGGL(k_pre, dim3(XB + 162), dim3(512), 0, stream,
                       x, w_conv, w_off, wfrag, xpair, XB);
    if (mode == 2) {
        hipLaunchKernelGGL(k_off, dim3(512), dim3(256), 0, stream,
                           xpair, b_off, wfrag, pwt_g, pidx_g);
        hipLaunchKernelGGL((k_all<2>), dim3(512), dim3(512), 0, stream,
                           x, xpair, b_off, wfrag, out, pwt_g, pidx_g);
    } else if (mode == 1) {
        hipLaunchKernelGGL((k_all<1>), dim3(512), dim3(512), 0, stream,
                           x, xpair, b_off, wfrag, out, nullptr, nullptr);
    } else {
        hipLaunchKernelGGL((k_all<0>), dim3(512), dim3(512), 0, stream,
                           x, xpair, b_off, wfrag, out, nullptr, nullptr);
    }
}

// Round 6
// 154.303 us; speedup vs baseline: 1.1624x; 1.1624x over previous
//
#include <hip/hip_runtime.h>

// Modulated deformable conv, fp32 in/out. B=4, CIN=COUT=256, H=W=64, KS=3, PAD=1.
// R18: merge R17's k_off back into k_all (3 launches -> 2).
//  R17 post-mortem: k_all 82->59us (evicting phase1 worked) but the separate
//  k_off dispatch cost ~45-50us (runtime + 3rd-launch serialization) -- net loss.
//  This round: phase 1 = R17's verified barrier-free register gather-GEMM,
//  now across all 8 waves (m_sub x kquarter, both nt per wave = half the gather
//  traffic of k_off), partial sums reduced through a 16KB LDS alias, then the
//  proven 59us phase-3 body. Two kernels, no in-loop barriers in phase 1.
// ws: [xpairT 16MB][wfrag 1.33MB] = 18,104,320 B; MODE0 = direct-fp32 fallback.

#define WOFF_FRAG_OFF 589824
#define XPAIR_BYTES   16777216ull
#define WFRAG_BYTES   1327104ull

typedef unsigned short ushort_t;
typedef unsigned int   uint_t;

using short8 = __attribute__((ext_vector_type(8))) short;
using f32x4  = __attribute__((ext_vector_type(4))) float;
using uint4v = __attribute__((ext_vector_type(4))) uint_t;

struct __attribute__((packed, aligned(4))) pairf { float x, y; };

__device__ inline ushort_t f2bf(float v) {
    unsigned u = __float_as_uint(v);
    unsigned r = u + 0x7fffu + ((u >> 16) & 1u);   // RNE (inputs finite)
    return (ushort_t)(r >> 16);
}
__device__ inline float bflo(uint_t u) { return __uint_as_float(u << 16); }
__device__ inline float bfhi(uint_t u) { return __uint_as_float(u & 0xffff0000u); }

__device__ inline uint_t pk1(uint_t u0, uint_t u1, bool v) {
    return v ? ((u0 & 0xffffu) | (u1 << 16)) : 0u;
}
__device__ inline uint_t interp2(uint_t a0, uint_t a1, uint_t b0, uint_t b1, float4 wt) {
    const float v0 = (bflo(a0) * wt.x + bfhi(a0) * wt.y) * wt.z
                   + (bflo(a1) * wt.x + bfhi(a1) * wt.y) * wt.w;
    const float v1 = (bflo(b0) * wt.x + bfhi(b0) * wt.y) * wt.z
                   + (bflo(b1) * wt.x + bfhi(b1) * wt.y) * wt.w;
    return (uint_t)f2bf(v0) | ((uint_t)f2bf(v1) << 16);
}

// LDS-visibility barrier WITHOUT vmcnt drain: in-flight global loads survive.
#define BAR() do {                                              \
    asm volatile("s_waitcnt lgkmcnt(0)" ::: "memory");          \
    __builtin_amdgcn_s_barrier();                               \
    asm volatile("" ::: "memory");                              \
} while (0)

// k_pre: blocks [0,XB): xpairT tile-transpose; [XB,XB+144): w_conv frags;
// [XB+144,XB+162): w_off frags. All global stores coalesced 16B. 512 thr.
__global__ __launch_bounds__(512) void k_pre(
    const float* __restrict__ x,
    const float* __restrict__ w_conv,
    const float* __restrict__ w_off,
    ushort_t* __restrict__ wfrag,
    uint_t* __restrict__ xpair,
    int XB)
{
    __shared__ __align__(16) float xt[256 * 32];   // [cin][i^swz] fp32 tile, 32 KB
    __shared__ float xcol[256];                    // 33rd column (i==32)
    const int bid = blockIdx.x;
    const int t = threadIdx.x;
    if (bid < XB) {
        const int b = bid >> 7;
        const int idx0 = (bid & 127) << 5;           // 32 idx rows per block
        const float* xb = x + (b << 20);
#pragma unroll
        for (int r = 0; r < 4; ++r) {
            const int f = r * 512 + t;               // float4 id, 0..2047
            const int cin = f >> 3, k = f & 7;
            const float4 v = *(const float4*)&xb[(cin << 12) + idx0 + (k << 2)];
            const int swz = ((cin >> 2) & 7) << 2;   // XOR on i bits [2:4]
            *(float4*)&xt[(cin << 5) + ((k << 2) ^ swz)] = v;
        }
        if (t < 256)
            xcol[t] = ((idx0 & 63) == 0) ? xb[(t << 12) + idx0 + 32] : 0.f;
        __syncthreads();
        uint_t* op = xpair + (((b << 12) + idx0) << 8);
#pragma unroll
        for (int r = 0; r < 4; ++r) {
            const int g = r * 512 + t;               // uint4 id, 0..2047
            const int il = g >> 6, c4 = (g & 63) << 2;
            uint_t o[4];
#pragma unroll
            for (int j = 0; j < 4; ++j) {
                const int c = c4 + j;
                const int swz = ((c >> 2) & 7) << 2;
                const float lo = xt[(c << 5) + (il ^ swz)];
                const float hi = (il < 31) ? xt[(c << 5) + ((il + 1) ^ swz)]
                                           : xcol[c];
                o[j] = (uint_t)f2bf(lo) | ((uint_t)f2bf(hi) << 16);
            }
            *(uint4*)(op + (il << 8) + c4) = make_uint4(o[0], o[1], o[2], o[3]);
        }
        return;
    }
    const int wb = bid - XB;
    if (wb < 144) {                                   // w_conv fragment rows
        const int i8 = wb * 512 + t;                  // 0..73727
        const int lane = i8 & 63;
        const int nt = (i8 >> 6) & 15;
        const int kt = i8 >> 10;                      // 0..71
        const int n = nt * 16 + (lane & 15);
        const int k0 = kt * 32 + ((lane >> 4) << 3);
        ushort_t v[8];
#pragma unroll
        for (int j = 0; j < 8; ++j) {
            const int kn = k0 + j;                    // tap-outer: kn = tap*256+cin
            const int cin = kn & 255, tap = kn >> 8;
            v[j] = f2bf(w_conv[n * 2304 + cin * 9 + tap]);
        }
        uint4 o;
        o.x = (uint_t)v[0] | ((uint_t)v[1] << 16);
        o.y = (uint_t)v[2] | ((uint_t)v[3] << 16);
        o.z = (uint_t)v[4] | ((uint_t)v[5] << 16);
        o.w = (uint_t)v[6] | ((uint_t)v[7] << 16);
        *(uint4*)(wfrag + (size_t)i8 * 8) = o;
    } else {                                          // w_off fragment rows (+pad)
        const int i8 = (wb - 144) * 512 + t;          // 0..9215
        const int lane = i8 & 63;
        const int nt = (i8 >> 6) & 1;
        const int kt = i8 >> 7;                       // 0..71
        const int n = nt * 16 + (lane & 15);
        const int k0 = kt * 32 + ((lane >> 4) << 3);
        ushort_t v[8];
#pragma unroll
        for (int j = 0; j < 8; ++j) {
            const int kn = k0 + j;
            const int cin = kn & 255, tap = kn >> 8;
            v[j] = (n < 27) ? f2bf(w_off[n * 2304 + cin * 9 + tap]) : (ushort_t)0;
        }
        uint4 o;
        o.x = (uint_t)v[0] | ((uint_t)v[1] << 16);
        o.y = (uint_t)v[2] | ((uint_t)v[3] << 16);
        o.z = (uint_t)v[4] | ((uint_t)v[5] << 16);
        o.w = (uint_t)v[6] | ((uint_t)v[7] << 16);
        *(uint4*)(wfrag + WOFF_FRAG_OFF + (size_t)i8 * 8) = o;
    }
}

// ---- prefetch macros: explicit named uint4 scalars (NO arrays -> SROA-safe) ----
#define ISSUE3(tap) do {                                                     \
    const int2 ii_ = pidx[(tap) * 32 + px];                                  \
    const uint_t* p0_ = xq + (ii_.x << 8) + (slot << 4);                     \
    const uint_t* p1_ = xq + (ii_.y << 8) + (slot << 4);                     \
    r0a = *(const uint4*)(p0_);      r0b = *(const uint4*)(p0_ + 4);         \
    r0c = *(const uint4*)(p0_ + 8);  r0d = *(const uint4*)(p0_ + 12);        \
    r1a = *(const uint4*)(p1_);      r1b = *(const uint4*)(p1_ + 4);         \
    r1c = *(const uint4*)(p1_ + 8);  r1d = *(const uint4*)(p1_ + 12);        \
} while (0)

#define WRITE3(tap, bufi) do {                                               \
    const float4 wt_ = pwt[(tap) * 32 + px];                                 \
    uint_t* dst_ = (uint_t*)&As[bufi][0] + px * 132 + slot * 8;              \
    *(uint4*)dst_ = make_uint4(                                              \
        interp2(r0a.x, r1a.x, r0a.y, r1a.y, wt_),                            \
        interp2(r0a.z, r1a.z, r0a.w, r1a.w, wt_),                            \
        interp2(r0b.x, r1b.x, r0b.y, r1b.y, wt_),                            \
        interp2(r0b.z, r1b.z, r0b.w, r1b.w, wt_));                           \
    *(uint4*)(dst_ + 4) = make_uint4(                                        \
        interp2(r0c.x, r1c.x, r0c.y, r1c.y, wt_),                            \
        interp2(r0c.z, r1c.z, r0c.w, r1c.w, wt_),                            \
        interp2(r0d.x, r1d.x, r0d.y, r1d.y, wt_),                            \
        interp2(r0d.z, r1d.z, r0d.w, r1d.w, wt_));                           \
} while (0)

// ---- k_all: block = 32 px x 256 couts, 512 thr = 8 waves, grid 512 ----
// MODE 1: pair path, merged barrier-free offset-conv phase 1. MODE 0: direct.
template<int MODE>
__global__ __launch_bounds__(512, 4) void k_all(
    const float* __restrict__ x,
    const uint_t* __restrict__ xpair,
    const float* __restrict__ b_off,
    const ushort_t* __restrict__ wfrag,
    float* __restrict__ out)
{
    __shared__ short As[2][32 * 264];                // 33,792 B; px stride 264 shorts
    __shared__ __align__(16) float4 pwt[9 * 32];
    __shared__ __align__(16) int2   pidx[9 * 32];
    float* om_s = (float*)&As[0][0];                 // fp32 alias (MODE0 om / MODE1 pb)

    const int bid = blockIdx.x;
    const int sid = ((bid & 7) << 6) | (bid >> 3);   // XCD-contiguous bands
    const int m0  = sid << 5;
    const int b   = m0 >> 12;
    const int h   = (m0 >> 6) & 63;
    const int wbase = m0 & 63;                        // 0 or 32
    const int tid  = threadIdx.x;
    const int lane = tid & 63;
    const int wv   = tid >> 6;                        // 0..7
    const int quad = lane >> 4;
    const int px   = tid & 31;                        // staging pixel
    const int slot = tid >> 5;                        // 0..15: 16 cins each

    const float*  xb = x + (b << 20);
    const uint_t* xq = xpair + (b << 20);
    const ushort_t* woffb = wfrag + WOFF_FRAG_OFF;

    if constexpr (MODE == 1) {
        // ===== phase 1: barrier-free register gather-GEMM (all 8 waves) =====
        // wave = (m_sub = wv>>2, kq = wv&3); each wave: k2 in {2kq,2kq+1},
        // BOTH nt cout-tiles (2 accumulators). Verified math from R17's k_off.
        float* pb = om_s;                             // float[4][2][16][32] = 16 KB
        const int m_sub = wv >> 2;
        const int kq = wv & 3;
        const int pxl = (m_sub << 4) + (lane & 15);
        f32x4 oa0 = {0.f, 0.f, 0.f, 0.f}, oa1 = {0.f, 0.f, 0.f, 0.f};
        for (int tap = 0; tap < 9; ++tap) {
            const int ky = (tap * 11) >> 5, kx = tap - ky * 3;
            const int yy = h + ky - 1;
            const int xx = wbase + pxl + kx - 1;
            const bool v = ((unsigned)yy < 64u) & ((unsigned)xx < 64u);
            const int idx = v ? (yy << 6) + xx : 0;
            const uint_t mAll = v ? 0xffffffffu : 0u;
            const uint_t* pr = xq + (idx << 8);
#pragma unroll
            for (int j = 0; j < 2; ++j) {
                const int k2 = kq * 2 + j;
                const int cin0 = k2 * 32 + (quad << 3);
                const uint4v u0 = *(const uint4v*)(pr + cin0);
                const uint4v u1 = *(const uint4v*)(pr + cin0 + 4);
                uint4v pk;
                pk.x = __builtin_amdgcn_perm(u0.y, u0.x, 0x05040100u) & mAll;
                pk.y = __builtin_amdgcn_perm(u0.w, u0.z, 0x05040100u) & mAll;
                pk.z = __builtin_amdgcn_perm(u1.y, u1.x, 0x05040100u) & mAll;
                pk.w = __builtin_amdgcn_perm(u1.w, u1.z, 0x05040100u) & mAll;
                const short8 a = __builtin_bit_cast(short8, pk);
                const int ktg = tap * 8 + k2;
                const short8 bf0 = *(const short8*)(woffb + ((ktg * 2 + 0) * 64 + lane) * 8);
                const short8 bf1 = *(const short8*)(woffb + ((ktg * 2 + 1) * 64 + lane) * 8);
                oa0 = __builtin_amdgcn_mfma_f32_16x16x32_bf16(a, bf0, oa0, 0, 0, 0);
                oa1 = __builtin_amdgcn_mfma_f32_16x16x32_bf16(a, bf1, oa1, 0, 0, 0);
            }
        }
        // partials: pb[((kq*2+nt)*16 + c)*32 + px], c = lane&15, px = m_sub*16+quad*4+reg
        *(f32x4*)&pb[((kq * 2 + 0) * 16 + (lane & 15)) * 32 + (m_sub << 4) + (quad << 2)] = oa0;
        *(f32x4*)&pb[((kq * 2 + 1) * 16 + (lane & 15)) * 32 + (m_sub << 4) + (quad << 2)] = oa1;
        BAR();
        // ===== phase 2: params; om(cg,px) = sum over 4 kq partials ==========
        if (tid < 288) {
            const int p2 = tid & 31, tp = tid >> 5;
            const int ky = (tp * 11) >> 5, kx = tp - ky * 3;
            // layout collapses to base = cg*32 + px, kq stride = 1024 floats
#define RD4(cg) (pb[((cg) << 5) + p2] + pb[((cg) << 5) + p2 + 1024] \
               + pb[((cg) << 5) + p2 + 2048] + pb[((cg) << 5) + p2 + 3072])
            const float dyv = RD4(2 * tp) + b_off[2 * tp];
            const float dxv = RD4(2 * tp + 1) + b_off[2 * tp + 1];
            const float mo  = RD4(18 + tp) + b_off[18 + tp];
#undef RD4
            const float mv  = 1.f / (1.f + expf(-mo));
            const float py  = dyv + (float)(h - 1 + ky);
            const float pxf = dxv + (float)(wbase + p2 - 1 + kx);
            const float y0f = floorf(py), x0f = floorf(pxf);
            const float wy = py - y0f,    wx = pxf - x0f;
            const float vy0 = (y0f >=  0.f && y0f <= 63.f) ? 1.f : 0.f;
            const float vy1 = (y0f >= -1.f && y0f <= 62.f) ? 1.f : 0.f;
            const int ry0 = (int)fminf(fmaxf(y0f, 0.f), 63.f);
            const int ry1 = (int)fminf(fmaxf(y0f + 1.f, 0.f), 63.f);
            const float rw0 = (1.f - wy) * vy0 * mv;
            const float rw1 = wy * vy1 * mv;
            const bool in01 = (x0f >= 0.f && x0f <= 62.f);
            const float wa = in01 ? (1.f - wx) : ((x0f == -1.f) ? wx : 0.f);
            const float wb = in01 ? wx : ((x0f == 63.f) ? (1.f - wx) : 0.f);
            const int bx = (int)fminf(fmaxf(x0f, 0.f), 62.f);
            pwt[tid]  = make_float4(wa, wb, rw0, rw1);
            pidx[tid] = make_int2(ry0 * 64 + bx, ry1 * 64 + bx);
        }
        BAR();
    } else {
        // ===== MODE 0 fallback: direct-fp32 phase 1 (staged via LDS) ========
        const int m_w = wv & 1, nt_w = (wv >> 1) & 1;
        f32x4 om_acc = {0.f, 0.f, 0.f, 0.f};
        auto stage1 = [&](int tap, int bufi) {
            const int ky = (tap * 11) >> 5, kx = tap - ky * 3;
            const int yy = h + ky - 1;
            const int xx = wbase + px + kx - 1;
            const bool v = ((unsigned)yy < 64u) & ((unsigned)xx < 64u);
            const int idx = v ? (yy << 6) + xx : 0;
            uint_t lo16[16];
#pragma unroll
            for (int c = 0; c < 16; ++c) {
                const int cin = (slot << 4) + c;
                const float t0 = xb[(cin << 12) + idx];
                lo16[c] = v ? (uint_t)f2bf(t0) : 0u;
            }
            uint_t o[8];
#pragma unroll
            for (int k = 0; k < 8; ++k) o[k] = lo16[2 * k] | (lo16[2 * k + 1] << 16);
            uint_t* dst = (uint_t*)&As[bufi][0] + px * 132 + slot * 8;
            *(uint4*)dst       = make_uint4(o[0], o[1], o[2], o[3]);
            *(uint4*)(dst + 4) = make_uint4(o[4], o[5], o[6], o[7]);
        };
        auto mfma1 = [&](int tap) {
            if (wv < 4) {
                const short* cur = &As[tap & 1][0];
#pragma unroll
                for (int k2 = 0; k2 < 8; ++k2) {
                    const int ktg = tap * 8 + k2;
                    const short8 a = *(const short8*)&cur[((m_w << 4) + (lane & 15)) * 264 + k2 * 32 + quad * 8];
                    const short8 bf = *(const short8*)(woffb + ((ktg * 2 + nt_w) * 64 + lane) * 8);
                    om_acc = __builtin_amdgcn_mfma_f32_16x16x32_bf16(a, bf, om_acc, 0, 0, 0);
                }
            }
        };
        stage1(0, 0);
        __syncthreads();
        for (int tap = 0; tap < 9; ++tap) {
            if (tap < 8) stage1(tap + 1, (tap + 1) & 1);
            mfma1(tap);
            __syncthreads();
        }
        if (wv < 4) {
            const int c = (nt_w << 4) + (lane & 15);
            *(f32x4*)&om_s[c * 32 + (m_w << 4) + (quad << 2)] = om_acc;
        }
        __syncthreads();
        if (tid < 288) {
            const int p2 = tid & 31, tp = tid >> 5;
            const int ky = (tp * 11) >> 5, kx = tp - ky * 3;
            const float dyv = om_s[(2 * tp) * 32 + p2] + b_off[2 * tp];
            const float dxv = om_s[(2 * tp + 1) * 32 + p2] + b_off[2 * tp + 1];
            const float mo  = om_s[(18 + tp) * 32 + p2] + b_off[18 + tp];
            const float mv  = 1.f / (1.f + expf(-mo));
            const float py  = dyv + (float)(h - 1 + ky);
            const float pxf = dxv + (float)(wbase + p2 - 1 + kx);
            const float y0f = floorf(py), x0f = floorf(pxf);
            const float wy = py - y0f,    wx = pxf - x0f;
            const float vy0 = (y0f >=  0.f && y0f <= 63.f) ? 1.f : 0.f;
            const float vy1 = (y0f >= -1.f && y0f <= 62.f) ? 1.f : 0.f;
            const int ry0 = (int)fminf(fmaxf(y0f, 0.f), 63.f);
            const int ry1 = (int)fminf(fmaxf(y0f + 1.f, 0.f), 63.f);
            const float rw0 = (1.f - wy) * vy0 * mv;
            const float rw1 = wy * vy1 * mv;
            const bool in01 = (x0f >= 0.f && x0f <= 62.f);
            const float wa = in01 ? (1.f - wx) : ((x0f == -1.f) ? wx : 0.f);
            const float wb = in01 ? wx : ((x0f == 63.f) ? (1.f - wx) : 0.f);
            const int bx = (int)fminf(fmaxf(x0f, 0.f), 62.f);
            pwt[tid]  = make_float4(wa, wb, rw0, rw1);
            pidx[tid] = make_int2(ry0 * 64 + bx, ry1 * 64 + bx);
        }
        __syncthreads();
    }

    // ================= phase 3: sampling + main GEMM =================
    f32x4 acc00 = {0.f, 0.f, 0.f, 0.f}, acc01 = {0.f, 0.f, 0.f, 0.f};
    f32x4 acc10 = {0.f, 0.f, 0.f, 0.f}, acc11 = {0.f, 0.f, 0.f, 0.f};

    const int nt_base = wv << 1;                      // wave's couts: wv*32..+31

    if constexpr (MODE == 1) {
        uint4 r0a, r0b, r0c, r0d, r1a, r1b, r1c, r1d;
        ISSUE3(0);
        WRITE3(0, 0);                                // overwrites pb (dead now)
        ISSUE3(1);
        BAR();
        for (int tap = 0; tap < 9; ++tap) {
            if (tap < 8) WRITE3(tap + 1, (tap + 1) & 1);
            if (tap < 7) ISSUE3(tap + 2);            // in flight across MFMA+BAR
            const short* cur = &As[tap & 1][0];
#pragma unroll
            for (int k2 = 0; k2 < 8; ++k2) {
                const int ktg = tap * 8 + k2;
                const short8 a0v = *(const short8*)&cur[(lane & 15) * 264 + k2 * 32 + quad * 8];
                const short8 a1v = *(const short8*)&cur[((lane & 15) + 16) * 264 + k2 * 32 + quad * 8];
                const short8 bf0 = *(const short8*)(wfrag + ((ktg * 16 + nt_base) * 64 + lane) * 8);
                const short8 bf1 = *(const short8*)(wfrag + ((ktg * 16 + nt_base + 1) * 64 + lane) * 8);
                acc00 = __builtin_amdgcn_mfma_f32_16x16x32_bf16(a0v, bf0, acc00, 0, 0, 0);
                acc01 = __builtin_amdgcn_mfma_f32_16x16x32_bf16(a0v, bf1, acc01, 0, 0, 0);
                acc10 = __builtin_amdgcn_mfma_f32_16x16x32_bf16(a1v, bf0, acc10, 0, 0, 0);
                acc11 = __builtin_amdgcn_mfma_f32_16x16x32_bf16(a1v, bf1, acc11, 0, 0, 0);
            }
            BAR();
        }
    } else {
        auto stage3 = [&](int tap, int bufi) {
            const float4 wt = pwt[tap * 32 + px];
            const int2   ii = pidx[tap * 32 + px];
            uint_t o[8];
#pragma unroll
            for (int k = 0; k < 8; ++k) {
                ushort_t s[2];
#pragma unroll
                for (int u = 0; u < 2; ++u) {
                    const int cin = (slot << 4) + 2 * k + u;
                    const pairf pa = *(const pairf*)(xb + (cin << 12) + ii.x);
                    const pairf pb2 = *(const pairf*)(xb + (cin << 12) + ii.y);
                    const float v = (pa.x * wt.x + pa.y * wt.y) * wt.z
                                  + (pb2.x * wt.x + pb2.y * wt.y) * wt.w;
                    s[u] = f2bf(v);
                }
                o[k] = (uint_t)s[0] | ((uint_t)s[1] << 16);
            }
            uint_t* dst = (uint_t*)&As[bufi][0] + px * 132 + slot * 8;
            *(uint4*)dst       = make_uint4(o[0], o[1], o[2], o[3]);
            *(uint4*)(dst + 4) = make_uint4(o[4], o[5], o[6], o[7]);
        };
        auto mfma3 = [&](int tap) {
            const short* cur = &As[tap & 1][0];
#pragma unroll
            for (int k2 = 0; k2 < 8; ++k2) {
                const int ktg = tap * 8 + k2;
                const short8 a0v = *(const short8*)&cur[(lane & 15) * 264 + k2 * 32 + quad * 8];
                const short8 a1v = *(const short8*)&cur[((lane & 15) + 16) * 264 + k2 * 32 + quad * 8];
                const short8 bf0 = *(const short8*)(wfrag + ((ktg * 16 + nt_base) * 64 + lane) * 8);
                const short8 bf1 = *(const short8*)(wfrag + ((ktg * 16 + nt_base + 1) * 64 + lane) * 8);
                acc00 = __builtin_amdgcn_mfma_f32_16x16x32_bf16(a0v, bf0, acc00, 0, 0, 0);
                acc01 = __builtin_amdgcn_mfma_f32_16x16x32_bf16(a0v, bf1, acc01, 0, 0, 0);
                acc10 = __builtin_amdgcn_mfma_f32_16x16x32_bf16(a1v, bf0, acc10, 0, 0, 0);
                acc11 = __builtin_amdgcn_mfma_f32_16x16x32_bf16(a1v, bf1, acc11, 0, 0, 0);
            }
        };
        stage3(0, 0);
        __syncthreads();
        for (int tap = 0; tap < 9; ++tap) {
            if (tap < 8) stage3(tap + 1, (tap + 1) & 1);
            mfma3(tap);
            __syncthreads();
        }
    }

    // epilogue: w = wbase + m*16 + quad*4 + reg; cout n = wv*32 + nn*16 + (lane&15)
    {
        const int w0 = wbase + (quad << 2);
        const int w1 = wbase + 16 + (quad << 2);
        const int n0 = (wv << 5) + (lane & 15);
        const int n1 = (wv << 5) + 16 + (lane & 15);
        *(f32x4*)(out + (((size_t)((b << 8) + n0)) << 12) + (h << 6) + w0) = acc00;
        *(f32x4*)(out + (((size_t)((b << 8) + n1)) << 12) + (h << 6) + w0) = acc01;
        *(f32x4*)(out + (((size_t)((b << 8) + n0)) << 12) + (h << 6) + w1) = acc10;
        *(f32x4*)(out + (((size_t)((b << 8) + n1)) << 12) + (h << 6) + w1) = acc11;
    }
}

extern "C" void kernel_launch(void* const* d_in, const int* in_sizes, int n_in,
                              void* d_out, int out_size, void* d_ws, size_t ws_size,
                              hipStream_t stream) {
    const float* x      = (const float*)d_in[0];
    const float* w_off  = (const float*)d_in[1];
    const float* b_off  = (const float*)d_in[2];
    const float* w_conv = (const float*)d_in[3];
    float* out = (float*)d_out;

    const size_t need1 = XPAIR_BYTES + WFRAG_BYTES;   // 18,104,320
    const int mode = (ws_size >= need1) ? 1 : 0;

    uint_t*   xpair = (uint_t*)d_ws;
    ushort_t* wfrag = (mode >= 1) ? (ushort_t*)((char*)d_ws + XPAIR_BYTES)
                                  : (ushort_t*)d_ws;
    const int XB = (mode >= 1) ? 512 : 0;

    hipLaunchKernelGGL(k_pre, dim3(XB + 162), dim3(512), 0, stream,
                       x, w_conv, w_off, wfrag, xpair, XB);
    if (mode == 1)
        hipLaunchKernelGGL((k_all<1>), dim3(512), dim3(512), 0, stream,
                           x, xpair, b_off, wfrag, out);
    else
        hipLaunchKernelGGL((k_all<0>), dim3(512), dim3(512), 0, stream,
                           x, xpair, b_off, wfrag, out);
}

// Round 7
// 150.476 us; speedup vs baseline: 1.1920x; 1.0254x over previous
//
#include <hip/hip_runtime.h>

// Modulated deformable conv, fp32 in/out. B=4, CIN=COUT=256, H=W=64, KS=3, PAD=1.
// R19: M=64 block restructure (1024 thr, grid 256, 1 block/CU).
//  R18 post-mortem: phase3 L2-BW-bound on wfrag (M=32 -> 8:1 B:A traffic,
//  ~26us/CU L2 floor); VGPR pinned at 64 because 40KB LDS let the backend
//  target 4 blocks/CU (8 waves/EU) occupancy our 2-block/CU grid never used.
//  - block = 64px x 256couts, 16 waves, each wave 4 m-tiles x 1 nt: per-px
//    wfrag traffic HALVES. LDS 81.4KB (>80KB) forces 1 block/CU -> allocator
//    budget becomes 128 VGPR (same 16 waves/CU as before, nothing lost).
//  - phase 1: 2-deep software pipeline (named-scalar gathers + bf frags for
//    tap+1 in flight under tap's MFMAs), fully unrolled. Same accumulation
//    order as R18 -> bit-identical output.
// ws: [xpairT 16MB][wfrag 1.33MB] = 18,104,320 B; k_fb = direct-fp32 fallback.

#define WOFF_FRAG_OFF 589824
#define XPAIR_BYTES   16777216ull
#define WFRAG_BYTES   1327104ull

typedef unsigned short ushort_t;
typedef unsigned int   uint_t;

using short8 = __attribute__((ext_vector_type(8))) short;
using f32x4  = __attribute__((ext_vector_type(4))) float;
using uint4v = __attribute__((ext_vector_type(4))) uint_t;

struct __attribute__((packed, aligned(4))) pairf { float x, y; };

__device__ inline ushort_t f2bf(float v) {
    unsigned u = __float_as_uint(v);
    unsigned r = u + 0x7fffu + ((u >> 16) & 1u);   // RNE (inputs finite)
    return (ushort_t)(r >> 16);
}
__device__ inline float bflo(uint_t u) { return __uint_as_float(u << 16); }
__device__ inline float bfhi(uint_t u) { return __uint_as_float(u & 0xffff0000u); }

__device__ inline uint_t interp2(uint_t a0, uint_t a1, uint_t b0, uint_t b1, float4 wt) {
    const float v0 = (bflo(a0) * wt.x + bfhi(a0) * wt.y) * wt.z
                   + (bflo(a1) * wt.x + bfhi(a1) * wt.y) * wt.w;
    const float v1 = (bflo(b0) * wt.x + bfhi(b0) * wt.y) * wt.z
                   + (bflo(b1) * wt.x + bfhi(b1) * wt.y) * wt.w;
    return (uint_t)f2bf(v0) | ((uint_t)f2bf(v1) << 16);
}

// LDS-visibility barrier WITHOUT vmcnt drain: in-flight global loads survive.
#define BAR() do {                                              \
    asm volatile("s_waitcnt lgkmcnt(0)" ::: "memory");          \
    __builtin_amdgcn_s_barrier();                               \
    asm volatile("" ::: "memory");                              \
} while (0)

// k_pre: blocks [0,XB): xpairT tile-transpose; [XB,XB+144): w_conv frags;
// [XB+144,XB+162): w_off frags. All global stores coalesced 16B. 512 thr.
__global__ __launch_bounds__(512) void k_pre(
    const float* __restrict__ x,
    const float* __restrict__ w_conv,
    const float* __restrict__ w_off,
    ushort_t* __restrict__ wfrag,
    uint_t* __restrict__ xpair,
    int XB)
{
    __shared__ __align__(16) float xt[256 * 32];   // [cin][i^swz] fp32 tile, 32 KB
    __shared__ float xcol[256];                    // 33rd column (i==32)
    const int bid = blockIdx.x;
    const int t = threadIdx.x;
    if (bid < XB) {
        const int b = bid >> 7;
        const int idx0 = (bid & 127) << 5;           // 32 idx rows per block
        const float* xb = x + (b << 20);
#pragma unroll
        for (int r = 0; r < 4; ++r) {
            const int f = r * 512 + t;               // float4 id, 0..2047
            const int cin = f >> 3, k = f & 7;
            const float4 v = *(const float4*)&xb[(cin << 12) + idx0 + (k << 2)];
            const int swz = ((cin >> 2) & 7) << 2;   // XOR on i bits [2:4]
            *(float4*)&xt[(cin << 5) + ((k << 2) ^ swz)] = v;
        }
        if (t < 256)
            xcol[t] = ((idx0 & 63) == 0) ? xb[(t << 12) + idx0 + 32] : 0.f;
        __syncthreads();
        uint_t* op = xpair + (((b << 12) + idx0) << 8);
#pragma unroll
        for (int r = 0; r < 4; ++r) {
            const int g = r * 512 + t;               // uint4 id, 0..2047
            const int il = g >> 6, c4 = (g & 63) << 2;
            uint_t o[4];
#pragma unroll
            for (int j = 0; j < 4; ++j) {
                const int c = c4 + j;
                const int swz = ((c >> 2) & 7) << 2;
                const float lo = xt[(c << 5) + (il ^ swz)];
                const float hi = (il < 31) ? xt[(c << 5) + ((il + 1) ^ swz)]
                                           : xcol[c];
                o[j] = (uint_t)f2bf(lo) | ((uint_t)f2bf(hi) << 16);
            }
            *(uint4*)(op + (il << 8) + c4) = make_uint4(o[0], o[1], o[2], o[3]);
        }
        return;
    }
    const int wb = bid - XB;
    if (wb < 144) {                                   // w_conv fragment rows
        const int i8 = wb * 512 + t;                  // 0..73727
        const int lane = i8 & 63;
        const int nt = (i8 >> 6) & 15;
        const int kt = i8 >> 10;                      // 0..71
        const int n = nt * 16 + (lane & 15);
        const int k0 = kt * 32 + ((lane >> 4) << 3);
        ushort_t v[8];
#pragma unroll
        for (int j = 0; j < 8; ++j) {
            const int kn = k0 + j;                    // tap-outer: kn = tap*256+cin
            const int cin = kn & 255, tap = kn >> 8;
            v[j] = f2bf(w_conv[n * 2304 + cin * 9 + tap]);
        }
        uint4 o;
        o.x = (uint_t)v[0] | ((uint_t)v[1] << 16);
        o.y = (uint_t)v[2] | ((uint_t)v[3] << 16);
        o.z = (uint_t)v[4] | ((uint_t)v[5] << 16);
        o.w = (uint_t)v[6] | ((uint_t)v[7] << 16);
        *(uint4*)(wfrag + (size_t)i8 * 8) = o;
    } else {                                          // w_off fragment rows (+pad)
        const int i8 = (wb - 144) * 512 + t;          // 0..9215
        const int lane = i8 & 63;
        const int nt = (i8 >> 6) & 1;
        const int kt = i8 >> 7;                       // 0..71
        const int n = nt * 16 + (lane & 15);
        const int k0 = kt * 32 + ((lane >> 4) << 3);
        ushort_t v[8];
#pragma unroll
        for (int j = 0; j < 8; ++j) {
            const int kn = k0 + j;
            const int cin = kn & 255, tap = kn >> 8;
            v[j] = (n < 27) ? f2bf(w_off[n * 2304 + cin * 9 + tap]) : (ushort_t)0;
        }
        uint4 o;
        o.x = (uint_t)v[0] | ((uint_t)v[1] << 16);
        o.y = (uint_t)v[2] | ((uint_t)v[3] << 16);
        o.z = (uint_t)v[4] | ((uint_t)v[5] << 16);
        o.w = (uint_t)v[6] | ((uint_t)v[7] << 16);
        *(uint4*)(wfrag + WOFF_FRAG_OFF + (size_t)i8 * 8) = o;
    }
}

// ---- phase-1 pipeline macros (named scalars only; SROA-safe) ----
#define P1LOAD(tp, ga0, ga1, gb0, gb1, b00, b01, b10, b11, mk) do {          \
    const int ky_ = ((tp) * 11) >> 5, kx_ = (tp) - ky_ * 3;                  \
    const int yy_ = h + ky_ - 1;                                             \
    const int xx_ = pxl + kx_ - 1;                                           \
    const bool v_ = ((unsigned)yy_ < 64u) & ((unsigned)xx_ < 64u);           \
    const int idx_ = v_ ? (yy_ << 6) + xx_ : 0;                              \
    mk = v_ ? 0xffffffffu : 0u;                                              \
    const uint_t* pr_ = xq + (idx_ << 8) + (kq << 6) + (quad << 3);          \
    ga0 = *(const uint4*)(pr_);       ga1 = *(const uint4*)(pr_ + 4);        \
    gb0 = *(const uint4*)(pr_ + 32);  gb1 = *(const uint4*)(pr_ + 36);       \
    const int kt_ = ((tp) * 8 + kq * 2) * 2;                                 \
    b00 = *(const short8*)(woffb + ((kt_ + 0) * 64 + lane) * 8);             \
    b01 = *(const short8*)(woffb + ((kt_ + 1) * 64 + lane) * 8);             \
    b10 = *(const short8*)(woffb + ((kt_ + 2) * 64 + lane) * 8);             \
    b11 = *(const short8*)(woffb + ((kt_ + 3) * 64 + lane) * 8);             \
} while (0)

#define P1COMP(ga0, ga1, gb0, gb1, b00, b01, b10, b11, mk) do {              \
    uint4v pkA_;                                                             \
    pkA_.x = __builtin_amdgcn_perm((ga0).y, (ga0).x, 0x05040100u) & (mk);    \
    pkA_.y = __builtin_amdgcn_perm((ga0).w, (ga0).z, 0x05040100u) & (mk);    \
    pkA_.z = __builtin_amdgcn_perm((ga1).y, (ga1).x, 0x05040100u) & (mk);    \
    pkA_.w = __builtin_amdgcn_perm((ga1).w, (ga1).z, 0x05040100u) & (mk);    \
    const short8 aA_ = __builtin_bit_cast(short8, pkA_);                     \
    oa0 = __builtin_amdgcn_mfma_f32_16x16x32_bf16(aA_, b00, oa0, 0, 0, 0);   \
    oa1 = __builtin_amdgcn_mfma_f32_16x16x32_bf16(aA_, b01, oa1, 0, 0, 0);   \
    uint4v pkB_;                                                             \
    pkB_.x = __builtin_amdgcn_perm((gb0).y, (gb0).x, 0x05040100u) & (mk);    \
    pkB_.y = __builtin_amdgcn_perm((gb0).w, (gb0).z, 0x05040100u) & (mk);    \
    pkB_.z = __builtin_amdgcn_perm((gb1).y, (gb1).x, 0x05040100u) & (mk);    \
    pkB_.w = __builtin_amdgcn_perm((gb1).w, (gb1).z, 0x05040100u) & (mk);    \
    const short8 aB_ = __builtin_bit_cast(short8, pkB_);                     \
    oa0 = __builtin_amdgcn_mfma_f32_16x16x32_bf16(aB_, b10, oa0, 0, 0, 0);   \
    oa1 = __builtin_amdgcn_mfma_f32_16x16x32_bf16(aB_, b11, oa1, 0, 0, 0);   \
} while (0)

// ---- phase-3 prefetch macros (named scalars; M=64 layout) ----
#define ISSUE3(tap) do {                                                     \
    const int2 ii_ = pidx[(tap) * 64 + px];                                  \
    const uint_t* p0_ = xq + (ii_.x << 8) + (slot << 4);                     \
    const uint_t* p1_ = xq + (ii_.y << 8) + (slot << 4);                     \
    r0a = *(const uint4*)(p0_);      r0b = *(const uint4*)(p0_ + 4);         \
    r0c = *(const uint4*)(p0_ + 8);  r0d = *(const uint4*)(p0_ + 12);        \
    r1a = *(const uint4*)(p1_);      r1b = *(const uint4*)(p1_ + 4);         \
    r1c = *(const uint4*)(p1_ + 8);  r1d = *(const uint4*)(p1_ + 12);        \
} while (0)

#define WRITE3(tap, bufi) do {                                               \
    const float4 wt_ = pwt[(tap) * 64 + px];                                 \
    uint_t* dst_ = (uint_t*)&As[bufi][0] + px * 132 + slot * 8;              \
    *(uint4*)dst_ = make_uint4(                                              \
        interp2(r0a.x, r1a.x, r0a.y, r1a.y, wt_),                            \
        interp2(r0a.z, r1a.z, r0a.w, r1a.w, wt_),                            \
        interp2(r0b.x, r1b.x, r0b.y, r1b.y, wt_),                            \
        interp2(r0b.z, r1b.z, r0b.w, r1b.w, wt_));                           \
    *(uint4*)(dst_ + 4) = make_uint4(                                        \
        interp2(r0c.x, r1c.x, r0c.y, r1c.y, wt_),                            \
        interp2(r0c.z, r1c.z, r0c.w, r1c.w, wt_),                            \
        interp2(r0d.x, r1d.x, r0d.y, r1d.y, wt_),                            \
        interp2(r0d.z, r1d.z, r0d.w, r1d.w, wt_));                           \
} while (0)

// ---- k_main: block = 64 px (full W row) x 256 couts, 1024 thr = 16 waves ----
// grid 256 = 1 block/CU (LDS-forced). Wave wv: phase1 (m_sub=wv>>2, kq=wv&3);
// phase3 nt = wv, m-tiles 0..3.
__global__ __launch_bounds__(1024, 4) void k_main(
    const uint_t* __restrict__ xpair,
    const float* __restrict__ b_off,
    const ushort_t* __restrict__ wfrag,
    float* __restrict__ out)
{
    __shared__ short As[2][64 * 264];                // 67,584 B; px stride 264 shorts
    __shared__ __align__(16) float4 pwt[9 * 64];     // 9,216 B
    __shared__ __align__(16) int2   pidx[9 * 64];    // 4,608 B  (total 81,408 B)
    float* pb = (float*)&As[0][0];                   // phase-1 partials alias, 32 KB

    const int bid = blockIdx.x;
    const int sid = ((bid & 7) << 5) | (bid >> 3);   // XCD-contiguous bands
    const int b   = sid >> 6;
    const int h   = sid & 63;
    const int tid  = threadIdx.x;
    const int lane = tid & 63;
    const int wv   = tid >> 6;                        // 0..15
    const int quad = lane >> 4;
    const int px   = tid & 63;                        // staging pixel = lane
    const int slot = wv;                              // 16 cins per slot

    const uint_t* xq = xpair + (b << 20);
    const ushort_t* woffb = wfrag + WOFF_FRAG_OFF;

    // ===== phase 1: barrier-free pipelined register gather-GEMM =====
    const int m_sub = wv >> 2, kq = wv & 3;
    const int pxl = (m_sub << 4) + (lane & 15);       // 0..63
    f32x4 oa0 = {0.f, 0.f, 0.f, 0.f}, oa1 = {0.f, 0.f, 0.f, 0.f};
    {
        uint4 Aa0, Aa1, Ab0, Ab1, Ba0, Ba1, Bb0, Bb1;
        short8 Af00, Af01, Af10, Af11, Bf00, Bf01, Bf10, Bf11;
        uint_t Am, Bm;
        P1LOAD(0, Aa0, Aa1, Ab0, Ab1, Af00, Af01, Af10, Af11, Am);
#pragma unroll
        for (int tap = 0; tap < 9; ++tap) {
            if ((tap & 1) == 0) {
                if (tap < 8) P1LOAD(tap + 1, Ba0, Ba1, Bb0, Bb1, Bf00, Bf01, Bf10, Bf11, Bm);
                P1COMP(Aa0, Aa1, Ab0, Ab1, Af00, Af01, Af10, Af11, Am);
            } else {
                if (tap < 8) P1LOAD(tap + 1, Aa0, Aa1, Ab0, Ab1, Af00, Af01, Af10, Af11, Am);
                P1COMP(Ba0, Ba1, Bb0, Bb1, Bf00, Bf01, Bf10, Bf11, Bm);
            }
        }
    }
    // partials: pb[(kq*2048) + (nt*16 + c)*64 + px], c = lane&15
    *(f32x4*)&pb[((kq * 2 + 0) * 16 + (lane & 15)) * 64 + (m_sub << 4) + (quad << 2)] = oa0;
    *(f32x4*)&pb[((kq * 2 + 1) * 16 + (lane & 15)) * 64 + (m_sub << 4) + (quad << 2)] = oa1;
    BAR();

    // ===== phase 2: params; om(cg,px) = sum over 4 kq partials =====
    if (tid < 576) {
        const int p2 = tid & 63, tp = tid >> 6;
        const int ky = (tp * 11) >> 5, kx = tp - ky * 3;
#define RD4(cg) (pb[((cg) << 6) + p2] + pb[((cg) << 6) + p2 + 2048] \
               + pb[((cg) << 6) + p2 + 4096] + pb[((cg) << 6) + p2 + 6144])
        const float dyv = RD4(2 * tp) + b_off[2 * tp];
        const float dxv = RD4(2 * tp + 1) + b_off[2 * tp + 1];
        const float mo  = RD4(18 + tp) + b_off[18 + tp];
#undef RD4
        const float mv  = 1.f / (1.f + expf(-mo));
        const float py  = dyv + (float)(h - 1 + ky);
        const float pxf = dxv + (float)(p2 - 1 + kx);
        const float y0f = floorf(py), x0f = floorf(pxf);
        const float wy = py - y0f,    wx = pxf - x0f;
        const float vy0 = (y0f >=  0.f && y0f <= 63.f) ? 1.f : 0.f;
        const float vy1 = (y0f >= -1.f && y0f <= 62.f) ? 1.f : 0.f;
        const int ry0 = (int)fminf(fmaxf(y0f, 0.f), 63.f);
        const int ry1 = (int)fminf(fmaxf(y0f + 1.f, 0.f), 63.f);
        const float rw0 = (1.f - wy) * vy0 * mv;
        const float rw1 = wy * vy1 * mv;
        const bool in01 = (x0f >= 0.f && x0f <= 62.f);
        const float wa = in01 ? (1.f - wx) : ((x0f == -1.f) ? wx : 0.f);
        const float wb = in01 ? wx : ((x0f == 63.f) ? (1.f - wx) : 0.f);
        const int bx = (int)fminf(fmaxf(x0f, 0.f), 62.f);
        pwt[tid]  = make_float4(wa, wb, rw0, rw1);
        pidx[tid] = make_int2(ry0 * 64 + bx, ry1 * 64 + bx);
    }
    BAR();

    // ===== phase 3: sampling + main GEMM (wave: 4 m-tiles x nt=wv) =====
    f32x4 acc0 = {0.f, 0.f, 0.f, 0.f}, acc1 = {0.f, 0.f, 0.f, 0.f};
    f32x4 acc2 = {0.f, 0.f, 0.f, 0.f}, acc3 = {0.f, 0.f, 0.f, 0.f};
    {
        uint4 r0a, r0b, r0c, r0d, r1a, r1b, r1c, r1d;
        ISSUE3(0);
        WRITE3(0, 0);                                // overwrites pb (dead now)
        ISSUE3(1);
        BAR();
        for (int tap = 0; tap < 9; ++tap) {
            if (tap < 8) WRITE3(tap + 1, (tap + 1) & 1);
            if (tap < 7) ISSUE3(tap + 2);            // in flight across MFMA+BAR
            const short* cur = &As[tap & 1][0];
#pragma unroll
            for (int k2 = 0; k2 < 8; ++k2) {
                const int ktg = tap * 8 + k2;
                const short8 bf  = *(const short8*)(wfrag + ((ktg * 16 + wv) * 64 + lane) * 8);
                const short8 a0v = *(const short8*)&cur[((lane & 15)) * 264 + k2 * 32 + quad * 8];
                const short8 a1v = *(const short8*)&cur[((lane & 15) + 16) * 264 + k2 * 32 + quad * 8];
                const short8 a2v = *(const short8*)&cur[((lane & 15) + 32) * 264 + k2 * 32 + quad * 8];
                const short8 a3v = *(const short8*)&cur[((lane & 15) + 48) * 264 + k2 * 32 + quad * 8];
                acc0 = __builtin_amdgcn_mfma_f32_16x16x32_bf16(a0v, bf, acc0, 0, 0, 0);
                acc1 = __builtin_amdgcn_mfma_f32_16x16x32_bf16(a1v, bf, acc1, 0, 0, 0);
                acc2 = __builtin_amdgcn_mfma_f32_16x16x32_bf16(a2v, bf, acc2, 0, 0, 0);
                acc3 = __builtin_amdgcn_mfma_f32_16x16x32_bf16(a3v, bf, acc3, 0, 0, 0);
            }
            BAR();
        }
    }

    // epilogue: w = m*16 + quad*4 + reg; cout n = wv*16 + (lane&15)
    {
        const int n = (wv << 4) + (lane & 15);
        float* ob = out + (((size_t)((b << 8) + n)) << 12) + (h << 6);
        *(f32x4*)(ob + (quad << 2))      = acc0;
        *(f32x4*)(ob + 16 + (quad << 2)) = acc1;
        *(f32x4*)(ob + 32 + (quad << 2)) = acc2;
        *(f32x4*)(ob + 48 + (quad << 2)) = acc3;
    }
}

// ---- k_fb: direct-fp32 fallback (R18 MODE0), 512 thr, grid 512 ----
__global__ __launch_bounds__(512, 4) void k_fb(
    const float* __restrict__ x,
    const float* __restrict__ b_off,
    const ushort_t* __restrict__ wfrag,
    float* __restrict__ out)
{
    __shared__ short As[2][32 * 264];
    __shared__ __align__(16) float4 pwt[9 * 32];
    __shared__ __align__(16) int2   pidx[9 * 32];
    float* om_s = (float*)&As[0][0];

    const int bid = blockIdx.x;
    const int sid = ((bid & 7) << 6) | (bid >> 3);
    const int m0  = sid << 5;
    const int b   = m0 >> 12;
    const int h   = (m0 >> 6) & 63;
    const int wbase = m0 & 63;
    const int tid  = threadIdx.x;
    const int lane = tid & 63;
    const int wv   = tid >> 6;
    const int quad = lane >> 4;
    const int px   = tid & 31;
    const int slot = tid >> 5;

    const float*  xb = x + (b << 20);
    const ushort_t* woffb = wfrag + WOFF_FRAG_OFF;

    const int m_w = wv & 1, nt_w = (wv >> 1) & 1;
    f32x4 om_acc = {0.f, 0.f, 0.f, 0.f};
    auto stage1 = [&](int tap, int bufi) {
        const int ky = (tap * 11) >> 5, kx = tap - ky * 3;
        const int yy = h + ky - 1;
        const int xx = wbase + px + kx - 1;
        const bool v = ((unsigned)yy < 64u) & ((unsigned)xx < 64u);
        const int idx = v ? (yy << 6) + xx : 0;
        uint_t lo16[16];
#pragma unroll
        for (int c = 0; c < 16; ++c) {
            const int cin = (slot << 4) + c;
            const float t0 = xb[(cin << 12) + idx];
            lo16[c] = v ? (uint_t)f2bf(t0) : 0u;
        }
        uint_t o[8];
#pragma unroll
        for (int k = 0; k < 8; ++k) o[k] = lo16[2 * k] | (lo16[2 * k + 1] << 16);
        uint_t* dst = (uint_t*)&As[bufi][0] + px * 132 + slot * 8;
        *(uint4*)dst       = make_uint4(o[0], o[1], o[2], o[3]);
        *(uint4*)(dst + 4) = make_uint4(o[4], o[5], o[6], o[7]);
    };
    auto mfma1 = [&](int tap) {
        if (wv < 4) {
            const short* cur = &As[tap & 1][0];
#pragma unroll
            for (int k2 = 0; k2 < 8; ++k2) {
                const int ktg = tap * 8 + k2;
                const short8 a = *(const short8*)&cur[((m_w << 4) + (lane & 15)) * 264 + k2 * 32 + quad * 8];
                const short8 bf = *(const short8*)(woffb + ((ktg * 2 + nt_w) * 64 + lane) * 8);
                om_acc = __builtin_amdgcn_mfma_f32_16x16x32_bf16(a, bf, om_acc, 0, 0, 0);
            }
        }
    };
    stage1(0, 0);
    __syncthreads();
    for (int tap = 0; tap < 9; ++tap) {
        if (tap < 8) stage1(tap + 1, (tap + 1) & 1);
        mfma1(tap);
        __syncthreads();
    }
    if (wv < 4) {
        const int c = (nt_w << 4) + (lane & 15);
        *(f32x4*)&om_s[c * 32 + (m_w << 4) + (quad << 2)] = om_acc;
    }
    __syncthreads();
    if (tid < 288) {
        const int p2 = tid & 31, tp = tid >> 5;
        const int ky = (tp * 11) >> 5, kx = tp - ky * 3;
        const float dyv = om_s[(2 * tp) * 32 + p2] + b_off[2 * tp];
        const float dxv = om_s[(2 * tp + 1) * 32 + p2] + b_off[2 * tp + 1];
        const float mo  = om_s[(18 + tp) * 32 + p2] + b_off[18 + tp];
        const float mv  = 1.f / (1.f + expf(-mo));
        const float py  = dyv + (float)(h - 1 + ky);
        const float pxf = dxv + (float)(wbase + p2 - 1 + kx);
        const float y0f = floorf(py), x0f = floorf(pxf);
        const float wy = py - y0f,    wx = pxf - x0f;
        const float vy0 = (y0f >=  0.f && y0f <= 63.f) ? 1.f : 0.f;
        const float vy1 = (y0f >= -1.f && y0f <= 62.f) ? 1.f : 0.f;
        const int ry0 = (int)fminf(fmaxf(y0f, 0.f), 63.f);
        const int ry1 = (int)fminf(fmaxf(y0f + 1.f, 0.f), 63.f);
        const float rw0 = (1.f - wy) * vy0 * mv;
        const float rw1 = wy * vy1 * mv;
        const bool in01 = (x0f >= 0.f && x0f <= 62.f);
        const float wa = in01 ? (1.f - wx) : ((x0f == -1.f) ? wx : 0.f);
        const float wb = in01 ? wx : ((x0f == 63.f) ? (1.f - wx) : 0.f);
        const int bx = (int)fminf(fmaxf(x0f, 0.f), 62.f);
        pwt[tid]  = make_float4(wa, wb, rw0, rw1);
        pidx[tid] = make_int2(ry0 * 64 + bx, ry1 * 64 + bx);
    }
    __syncthreads();

    f32x4 acc00 = {0.f, 0.f, 0.f, 0.f}, acc01 = {0.f, 0.f, 0.f, 0.f};
    f32x4 acc10 = {0.f, 0.f, 0.f, 0.f}, acc11 = {0.f, 0.f, 0.f, 0.f};
    const int nt_base = wv << 1;
    auto stage3 = [&](int tap, int bufi) {
        const float4 wt = pwt[tap * 32 + px];
        const int2   ii = pidx[tap * 32 + px];
        uint_t o[8];
#pragma unroll
        for (int k = 0; k < 8; ++k) {
            ushort_t s[2];
#pragma unroll
            for (int u = 0; u < 2; ++u) {
                const int cin = (slot << 4) + 2 * k + u;
                const pairf pa = *(const pairf*)(xb + (cin << 12) + ii.x);
                const pairf pb2 = *(const pairf*)(xb + (cin << 12) + ii.y);
                const float v = (pa.x * wt.x + pa.y * wt.y) * wt.z
                              + (pb2.x * wt.x + pb2.y * wt.y) * wt.w;
                s[u] = f2bf(v);
            }
            o[k] = (uint_t)s[0] | ((uint_t)s[1] << 16);
        }
        uint_t* dst = (uint_t*)&As[bufi][0] + px * 132 + slot * 8;
        *(uint4*)dst       = make_uint4(o[0], o[1], o[2], o[3]);
        *(uint4*)(dst + 4) = make_uint4(o[4], o[5], o[6], o[7]);
    };
    auto mfma3 = [&](int tap) {
        const short* cur = &As[tap & 1][0];
#pragma unroll
        for (int k2 = 0; k2 < 8; ++k2) {
            const int ktg = tap * 8 + k2;
            const short8 a0v = *(const short8*)&cur[(lane & 15) * 264 + k2 * 32 + quad * 8];
            const short8 a1v = *(const short8*)&cur[((lane & 15) + 16) * 264 + k2 * 32 + quad * 8];
            const short8 bf0 = *(const short8*)(wfrag + ((ktg * 16 + nt_base) * 64 + lane) * 8);
            const short8 bf1 = *(const short8*)(wfrag + ((ktg * 16 + nt_base + 1) * 64 + lane) * 8);
            acc00 = __builtin_amdgcn_mfma_f32_16x16x32_bf16(a0v, bf0, acc00, 0, 0, 0);
            acc01 = __builtin_amdgcn_mfma_f32_16x16x32_bf16(a0v, bf1, acc01, 0, 0, 0);
            acc10 = __builtin_amdgcn_mfma_f32_16x16x32_bf16(a1v, bf0, acc10, 0, 0, 0);
            acc11 = __builtin_amdgcn_mfma_f32_16x16x32_bf16(a1v, bf1, acc11, 0, 0, 0);
        }
    };
    stage3(0, 0);
    __syncthreads();
    for (int tap = 0; tap < 9; ++tap) {
        if (tap < 8) stage3(tap + 1, (tap + 1) & 1);
        mfma3(tap);
        __syncthreads();
    }
    {
        const int w0 = wbase + (quad << 2);
        const int w1 = wbase + 16 + (quad << 2);
        const int n0 = (wv << 5) + (lane & 15);
        const int n1 = (wv << 5) + 16 + (lane & 15);
        *(f32x4*)(out + (((size_t)((b << 8) + n0)) << 12) + (h << 6) + w0) = acc00;
        *(f32x4*)(out + (((size_t)((b << 8) + n1)) << 12) + (h << 6) + w0) = acc01;
        *(f32x4*)(out + (((size_t)((b << 8) + n0)) << 12) + (h << 6) + w1) = acc10;
        *(f32x4*)(out + (((size_t)((b << 8) + n1)) << 12) + (h << 6) + w1) = acc11;
    }
}

extern "C" void kernel_launch(void* const* d_in, const int* in_sizes, int n_in,
                              void* d_out, int out_size, void* d_ws, size_t ws_size,
                              hipStream_t stream) {
    const float* x      = (const float*)d_in[0];
    const float* w_off  = (const float*)d_in[1];
    const float* b_off  = (const float*)d_in[2];
    const float* w_conv = (const float*)d_in[3];
    float* out = (float*)d_out;

    const size_t need1 = XPAIR_BYTES + WFRAG_BYTES;   // 18,104,320
    const int mode = (ws_size >= need1) ? 1 : 0;

    uint_t*   xpair = (uint_t*)d_ws;
    ushort_t* wfrag = (mode >= 1) ? (ushort_t*)((char*)d_ws + XPAIR_BYTES)
                                  : (ushort_t*)d_ws;
    const int XB = (mode >= 1) ? 512 : 0;

    hipLaunchKernelGGL(k_pre, dim3(XB + 162), dim3(512), 0, stream,
                       x, w_conv, w_off, wfrag, xpair, XB);
    if (mode == 1)
        hipLaunchKernelGGL(k_main, dim3(256), dim3(1024), 0, stream,
                           xpair, b_off, wfrag, out);
    else
        hipLaunchKernelGGL(k_fb, dim3(512), dim3(512), 0, stream,
                           x, b_off, wfrag, out);
}

// Round 8
// 148.404 us; speedup vs baseline: 1.2086x; 1.0140x over previous
//
#include <hip/hip_runtime.h>

// Modulated deformable conv, fp32 in/out. B=4, CIN=COUT=256, H=W=64, KS=3, PAD=1.
// R20: R19 structure + inline-asm VMEM pipeline with counted vmcnt (T3/T4 style).
//  R19 post-mortem: allocator pins VGPR=60 at any budget and re-sinks loads;
//  in-order vmcnt exposes ~600cy L2 latency every round (bf consume waits the
//  just-issued gathers). Fix: ALL loop VMEM is asm global_load_dwordx4 into
//  named ext-vector regs; counted s_waitcnt vmcnt(8) (never 0 mid-loop) +
//  sched_barrier(0) after each wait (rule 18). Exact queue: per round
//  [wait GA(t+1)|8] WRITE3 [issue GA(t+2)] [wait BF(t)|8] MFMA [issue BF(t+1)] BAR.
//  Phase 1: A/B two-set rotation, same discipline. Math identical to R19.
// ws: [xpairT 16MB][wfrag 1.33MB] = 18,104,320 B; k_fb = direct-fp32 fallback.

#define WOFF_FRAG_OFF 589824
#define XPAIR_BYTES   16777216ull
#define WFRAG_BYTES   1327104ull

typedef unsigned short ushort_t;
typedef unsigned int   uint_t;

using short8 = __attribute__((ext_vector_type(8))) short;
using f32x4  = __attribute__((ext_vector_type(4))) float;
using uint4v = __attribute__((ext_vector_type(4))) uint_t;

struct __attribute__((packed, aligned(4))) pairf { float x, y; };

__device__ inline ushort_t f2bf(float v) {
    unsigned u = __float_as_uint(v);
    unsigned r = u + 0x7fffu + ((u >> 16) & 1u);   // RNE (inputs finite)
    return (ushort_t)(r >> 16);
}
__device__ inline float bflo(uint_t u) { return __uint_as_float(u << 16); }
__device__ inline float bfhi(uint_t u) { return __uint_as_float(u & 0xffff0000u); }

__device__ inline uint_t interp2(uint_t a0, uint_t a1, uint_t b0, uint_t b1, float4 wt) {
    const float v0 = (bflo(a0) * wt.x + bfhi(a0) * wt.y) * wt.z
                   + (bflo(a1) * wt.x + bfhi(a1) * wt.y) * wt.w;
    const float v1 = (bflo(b0) * wt.x + bfhi(b0) * wt.y) * wt.z
                   + (bflo(b1) * wt.x + bfhi(b1) * wt.y) * wt.w;
    return (uint_t)f2bf(v0) | ((uint_t)f2bf(v1) << 16);
}

// LDS-visibility barrier WITHOUT vmcnt drain: in-flight global loads survive.
#define BAR() do {                                              \
    asm volatile("s_waitcnt lgkmcnt(0)" ::: "memory");          \
    __builtin_amdgcn_s_barrier();                               \
    asm volatile("" ::: "memory");                              \
} while (0)

// counted vmcnt + hard scheduling fence (rule 18)
#define VM8() do { asm volatile("s_waitcnt vmcnt(8)" ::: "memory"); \
                   __builtin_amdgcn_sched_barrier(0); } while (0)
#define VM0() do { asm volatile("s_waitcnt vmcnt(0)" ::: "memory"); \
                   __builtin_amdgcn_sched_barrier(0); } while (0)

// k_pre: blocks [0,XB): xpairT tile-transpose; [XB,XB+144): w_conv frags;
// [XB+144,XB+162): w_off frags. All global stores coalesced 16B. 512 thr.
__global__ __launch_bounds__(512) void k_pre(
    const float* __restrict__ x,
    const float* __restrict__ w_conv,
    const float* __restrict__ w_off,
    ushort_t* __restrict__ wfrag,
    uint_t* __restrict__ xpair,
    int XB)
{
    __shared__ __align__(16) float xt[256 * 32];   // [cin][i^swz] fp32 tile, 32 KB
    __shared__ float xcol[256];                    // 33rd column (i==32)
    const int bid = blockIdx.x;
    const int t = threadIdx.x;
    if (bid < XB) {
        const int b = bid >> 7;
        const int idx0 = (bid & 127) << 5;           // 32 idx rows per block
        const float* xb = x + (b << 20);
#pragma unroll
        for (int r = 0; r < 4; ++r) {
            const int f = r * 512 + t;               // float4 id, 0..2047
            const int cin = f >> 3, k = f & 7;
            const float4 v = *(const float4*)&xb[(cin << 12) + idx0 + (k << 2)];
            const int swz = ((cin >> 2) & 7) << 2;   // XOR on i bits [2:4]
            *(float4*)&xt[(cin << 5) + ((k << 2) ^ swz)] = v;
        }
        if (t < 256)
            xcol[t] = ((idx0 & 63) == 0) ? xb[(t << 12) + idx0 + 32] : 0.f;
        __syncthreads();
        uint_t* op = xpair + (((b << 12) + idx0) << 8);
#pragma unroll
        for (int r = 0; r < 4; ++r) {
            const int g = r * 512 + t;               // uint4 id, 0..2047
            const int il = g >> 6, c4 = (g & 63) << 2;
            uint_t o[4];
#pragma unroll
            for (int j = 0; j < 4; ++j) {
                const int c = c4 + j;
                const int swz = ((c >> 2) & 7) << 2;
                const float lo = xt[(c << 5) + (il ^ swz)];
                const float hi = (il < 31) ? xt[(c << 5) + ((il + 1) ^ swz)]
                                           : xcol[c];
                o[j] = (uint_t)f2bf(lo) | ((uint_t)f2bf(hi) << 16);
            }
            *(uint4*)(op + (il << 8) + c4) = make_uint4(o[0], o[1], o[2], o[3]);
        }
        return;
    }
    const int wb = bid - XB;
    if (wb < 144) {                                   // w_conv fragment rows
        const int i8 = wb * 512 + t;                  // 0..73727
        const int lane = i8 & 63;
        const int nt = (i8 >> 6) & 15;
        const int kt = i8 >> 10;                      // 0..71
        const int n = nt * 16 + (lane & 15);
        const int k0 = kt * 32 + ((lane >> 4) << 3);
        ushort_t v[8];
#pragma unroll
        for (int j = 0; j < 8; ++j) {
            const int kn = k0 + j;                    // tap-outer: kn = tap*256+cin
            const int cin = kn & 255, tap = kn >> 8;
            v[j] = f2bf(w_conv[n * 2304 + cin * 9 + tap]);
        }
        uint4 o;
        o.x = (uint_t)v[0] | ((uint_t)v[1] << 16);
        o.y = (uint_t)v[2] | ((uint_t)v[3] << 16);
        o.z = (uint_t)v[4] | ((uint_t)v[5] << 16);
        o.w = (uint_t)v[6] | ((uint_t)v[7] << 16);
        *(uint4*)(wfrag + (size_t)i8 * 8) = o;
    } else {                                          // w_off fragment rows (+pad)
        const int i8 = (wb - 144) * 512 + t;          // 0..9215
        const int lane = i8 & 63;
        const int nt = (i8 >> 6) & 1;
        const int kt = i8 >> 7;                       // 0..71
        const int n = nt * 16 + (lane & 15);
        const int k0 = kt * 32 + ((lane >> 4) << 3);
        ushort_t v[8];
#pragma unroll
        for (int j = 0; j < 8; ++j) {
            const int kn = k0 + j;
            const int cin = kn & 255, tap = kn >> 8;
            v[j] = (n < 27) ? f2bf(w_off[n * 2304 + cin * 9 + tap]) : (ushort_t)0;
        }
        uint4 o;
        o.x = (uint_t)v[0] | ((uint_t)v[1] << 16);
        o.y = (uint_t)v[2] | ((uint_t)v[3] << 16);
        o.z = (uint_t)v[4] | ((uint_t)v[5] << 16);
        o.w = (uint_t)v[6] | ((uint_t)v[7] << 16);
        *(uint4*)(wfrag + WOFF_FRAG_OFF + (size_t)i8 * 8) = o;
    }
}

// ---- phase-1 asm pipeline: issue one tap's 4 gathers + 4 bf frags ----
#define P1_ISSUE(T, GA0, GA1, GB0, GB1, F0, F1, F2, F3, MK) do {             \
    const int ky_ = ((T) * 11) >> 5, kx_ = (T) - ky_ * 3;                    \
    const int yy_ = h + ky_ - 1;                                             \
    const int xx_ = pxl + kx_ - 1;                                           \
    const bool v_ = ((unsigned)yy_ < 64u) & ((unsigned)xx_ < 64u);           \
    const int idx_ = v_ ? (yy_ << 6) + xx_ : 0;                              \
    MK = v_ ? 0xffffffffu : 0u;                                              \
    const uint_t og_ = ((uint_t)b << 22) + ((uint_t)idx_ << 10)              \
                     + ((uint_t)kq << 8) + ((uint_t)quad << 5);              \
    asm volatile("global_load_dwordx4 %0, %1, %2"            : "=v"(GA0) : "v"(og_), "s"(xpair)); \
    asm volatile("global_load_dwordx4 %0, %1, %2 offset:16"  : "=v"(GA1) : "v"(og_), "s"(xpair)); \
    asm volatile("global_load_dwordx4 %0, %1, %2 offset:128" : "=v"(GB0) : "v"(og_), "s"(xpair)); \
    asm volatile("global_load_dwordx4 %0, %1, %2 offset:144" : "=v"(GB1) : "v"(og_), "s"(xpair)); \
    const uint_t of_ = 1179648u + (uint_t)(((((T) * 8 + kq * 2) * 2) * 64 + lane) * 16); \
    asm volatile("global_load_dwordx4 %0, %1, %2"             : "=v"(F0) : "v"(of_), "s"(wfrag)); \
    asm volatile("global_load_dwordx4 %0, %1, %2 offset:1024" : "=v"(F1) : "v"(of_), "s"(wfrag)); \
    asm volatile("global_load_dwordx4 %0, %1, %2 offset:2048" : "=v"(F2) : "v"(of_), "s"(wfrag)); \
    asm volatile("global_load_dwordx4 %0, %1, %2 offset:3072" : "=v"(F3) : "v"(of_), "s"(wfrag)); \
} while (0)

#define P1_COMP(GA0, GA1, GB0, GB1, F0, F1, F2, F3, MK) do {                 \
    uint4v pkA_;                                                             \
    pkA_.x = __builtin_amdgcn_perm((GA0).y, (GA0).x, 0x05040100u) & (MK);    \
    pkA_.y = __builtin_amdgcn_perm((GA0).w, (GA0).z, 0x05040100u) & (MK);    \
    pkA_.z = __builtin_amdgcn_perm((GA1).y, (GA1).x, 0x05040100u) & (MK);    \
    pkA_.w = __builtin_amdgcn_perm((GA1).w, (GA1).z, 0x05040100u) & (MK);    \
    const short8 aA_ = __builtin_bit_cast(short8, pkA_);                     \
    oa0 = __builtin_amdgcn_mfma_f32_16x16x32_bf16(aA_, F0, oa0, 0, 0, 0);    \
    oa1 = __builtin_amdgcn_mfma_f32_16x16x32_bf16(aA_, F1, oa1, 0, 0, 0);    \
    uint4v pkB_;                                                             \
    pkB_.x = __builtin_amdgcn_perm((GB0).y, (GB0).x, 0x05040100u) & (MK);    \
    pkB_.y = __builtin_amdgcn_perm((GB0).w, (GB0).z, 0x05040100u) & (MK);    \
    pkB_.z = __builtin_amdgcn_perm((GB1).y, (GB1).x, 0x05040100u) & (MK);    \
    pkB_.w = __builtin_amdgcn_perm((GB1).w, (GB1).z, 0x05040100u) & (MK);    \
    const short8 aB_ = __builtin_bit_cast(short8, pkB_);                     \
    oa0 = __builtin_amdgcn_mfma_f32_16x16x32_bf16(aB_, F2, oa0, 0, 0, 0);    \
    oa1 = __builtin_amdgcn_mfma_f32_16x16x32_bf16(aB_, F3, oa1, 0, 0, 0);    \
} while (0)

#define P1_ISSUE_A(T) P1_ISSUE(T, Aa0, Aa1, Ab0, Ab1, Af0, Af1, Af2, Af3, mkA)
#define P1_ISSUE_B(T) P1_ISSUE(T, Ba0, Ba1, Bb0, Bb1, Bf0, Bf1, Bf2, Bf3, mkB)
#define P1_COMP_A()   P1_COMP(Aa0, Aa1, Ab0, Ab1, Af0, Af1, Af2, Af3, mkA)
#define P1_COMP_B()   P1_COMP(Ba0, Ba1, Bb0, Bb1, Bf0, Bf1, Bf2, Bf3, mkB)

// ---- phase-3 asm pipeline ----
#define GA_ISSUE(T) do {                                                     \
    const int2 ii_ = pidx[(T) * 64 + px];                                    \
    const uint_t bb_ = ((uint_t)b << 22) + ((uint_t)wv << 6);                \
    const uint_t o0_ = bb_ + ((uint_t)ii_.x << 10);                          \
    const uint_t o1_ = bb_ + ((uint_t)ii_.y << 10);                          \
    asm volatile("global_load_dwordx4 %0, %1, %2"           : "=v"(r0a) : "v"(o0_), "s"(xpair)); \
    asm volatile("global_load_dwordx4 %0, %1, %2 offset:16" : "=v"(r0b) : "v"(o0_), "s"(xpair)); \
    asm volatile("global_load_dwordx4 %0, %1, %2 offset:32" : "=v"(r0c) : "v"(o0_), "s"(xpair)); \
    asm volatile("global_load_dwordx4 %0, %1, %2 offset:48" : "=v"(r0d) : "v"(o0_), "s"(xpair)); \
    asm volatile("global_load_dwordx4 %0, %1, %2"           : "=v"(r1a) : "v"(o1_), "s"(xpair)); \
    asm volatile("global_load_dwordx4 %0, %1, %2 offset:16" : "=v"(r1b) : "v"(o1_), "s"(xpair)); \
    asm volatile("global_load_dwordx4 %0, %1, %2 offset:32" : "=v"(r1c) : "v"(o1_), "s"(xpair)); \
    asm volatile("global_load_dwordx4 %0, %1, %2 offset:48" : "=v"(r1d) : "v"(o1_), "s"(xpair)); \
} while (0)

#define BF_ISSUE(T) do {                                                     \
    const uint_t ob_ = (uint_t)(((((T) * 8) * 16 + wv) * 1024) + (lane << 4)); \
    asm volatile("global_load_dwordx4 %0, %1, %2" : "=v"(bf0r) : "v"(ob_),           "s"(wfrag)); \
    asm volatile("global_load_dwordx4 %0, %1, %2" : "=v"(bf1r) : "v"(ob_ + 16384u),  "s"(wfrag)); \
    asm volatile("global_load_dwordx4 %0, %1, %2" : "=v"(bf2r) : "v"(ob_ + 32768u),  "s"(wfrag)); \
    asm volatile("global_load_dwordx4 %0, %1, %2" : "=v"(bf3r) : "v"(ob_ + 49152u),  "s"(wfrag)); \
    asm volatile("global_load_dwordx4 %0, %1, %2" : "=v"(bf4r) : "v"(ob_ + 65536u),  "s"(wfrag)); \
    asm volatile("global_load_dwordx4 %0, %1, %2" : "=v"(bf5r) : "v"(ob_ + 81920u),  "s"(wfrag)); \
    asm volatile("global_load_dwordx4 %0, %1, %2" : "=v"(bf6r) : "v"(ob_ + 98304u),  "s"(wfrag)); \
    asm volatile("global_load_dwordx4 %0, %1, %2" : "=v"(bf7r) : "v"(ob_ + 114688u), "s"(wfrag)); \
} while (0)

#define WRITE3(T, BUFI) do {                                                 \
    const float4 wt_ = pwt[(T) * 64 + px];                                   \
    uint_t* dst_ = (uint_t*)&As[BUFI][0] + px * 132 + wv * 8;                \
    *(uint4*)dst_ = make_uint4(                                              \
        interp2(r0a.x, r1a.x, r0a.y, r1a.y, wt_),                            \
        interp2(r0a.z, r1a.z, r0a.w, r1a.w, wt_),                            \
        interp2(r0b.x, r1b.x, r0b.y, r1b.y, wt_),                            \
        interp2(r0b.z, r1b.z, r0b.w, r1b.w, wt_));                           \
    *(uint4*)(dst_ + 4) = make_uint4(                                        \
        interp2(r0c.x, r1c.x, r0c.y, r1c.y, wt_),                            \
        interp2(r0c.z, r1c.z, r0c.w, r1c.w, wt_),                            \
        interp2(r0d.x, r1d.x, r0d.y, r1d.y, wt_),                            \
        interp2(r0d.z, r1d.z, r0d.w, r1d.w, wt_));                           \
} while (0)

#define MSTEP(K2, BFR) do {                                                  \
    const short8 a0v = *(const short8*)&cur[((lane & 15)) * 264 + (K2) * 32 + quad * 8]; \
    const short8 a1v = *(const short8*)&cur[((lane & 15) + 16) * 264 + (K2) * 32 + quad * 8]; \
    const short8 a2v = *(const short8*)&cur[((lane & 15) + 32) * 264 + (K2) * 32 + quad * 8]; \
    const short8 a3v = *(const short8*)&cur[((lane & 15) + 48) * 264 + (K2) * 32 + quad * 8]; \
    acc0 = __builtin_amdgcn_mfma_f32_16x16x32_bf16(a0v, BFR, acc0, 0, 0, 0); \
    acc1 = __builtin_amdgcn_mfma_f32_16x16x32_bf16(a1v, BFR, acc1, 0, 0, 0); \
    acc2 = __builtin_amdgcn_mfma_f32_16x16x32_bf16(a2v, BFR, acc2, 0, 0, 0); \
    acc3 = __builtin_amdgcn_mfma_f32_16x16x32_bf16(a3v, BFR, acc3, 0, 0, 0); \
} while (0)

#define MFMA3(T) do {                                                        \
    const short* cur = &As[(T) & 1][0];                                      \
    MSTEP(0, bf0r); MSTEP(1, bf1r); MSTEP(2, bf2r); MSTEP(3, bf3r);          \
    MSTEP(4, bf4r); MSTEP(5, bf5r); MSTEP(6, bf6r); MSTEP(7, bf7r);          \
} while (0)

// round t = 0..6: wait GA(t+1) | write | issue GA(t+2) | wait BF(t) | mfma | issue BF(t+1)
#define R3_MID(T) do {                                                       \
    VM8(); WRITE3((T) + 1, ((T) + 1) & 1);                                   \
    GA_ISSUE((T) + 2);                                                       \
    VM8(); MFMA3(T);                                                         \
    BF_ISSUE((T) + 1);                                                       \
    BAR();                                                                   \
} while (0)

// ---- k_main: block = 64 px (full W row) x 256 couts, 1024 thr = 16 waves ----
__global__ __launch_bounds__(1024, 4) void k_main(
    const uint_t* __restrict__ xpair,
    const float* __restrict__ b_off,
    const ushort_t* __restrict__ wfrag,
    float* __restrict__ out)
{
    __shared__ short As[2][64 * 264];                // 67,584 B; px stride 264 shorts
    __shared__ __align__(16) float4 pwt[9 * 64];     // 9,216 B
    __shared__ __align__(16) int2   pidx[9 * 64];    // 4,608 B  (total 81,408 B)
    float* pb = (float*)&As[0][0];                   // phase-1 partials alias, 32 KB

    const int bid = blockIdx.x;
    const int sid = ((bid & 7) << 5) | (bid >> 3);   // XCD-contiguous bands
    const int b   = sid >> 6;
    const int h   = sid & 63;
    const int tid  = threadIdx.x;
    const int lane = tid & 63;
    const int wv   = tid >> 6;                        // 0..15
    const int quad = lane >> 4;
    const int px   = tid & 63;                        // staging pixel

    // ===== phase 1: asm-pipelined barrier-free register gather-GEMM =====
    const int m_sub = wv >> 2, kq = wv & 3;
    const int pxl = (m_sub << 4) + (lane & 15);       // 0..63 (16 px per m_sub? 0..31)
    f32x4 oa0 = {0.f, 0.f, 0.f, 0.f}, oa1 = {0.f, 0.f, 0.f, 0.f};
    {
        uint4v Aa0, Aa1, Ab0, Ab1, Ba0, Ba1, Bb0, Bb1;
        short8 Af0, Af1, Af2, Af3, Bf0, Bf1, Bf2, Bf3;
        uint_t mkA, mkB;
        VM0();
        P1_ISSUE_A(0);
        P1_ISSUE_B(1);
        VM8(); P1_COMP_A(); P1_ISSUE_A(2);
        VM8(); P1_COMP_B(); P1_ISSUE_B(3);
        VM8(); P1_COMP_A(); P1_ISSUE_A(4);
        VM8(); P1_COMP_B(); P1_ISSUE_B(5);
        VM8(); P1_COMP_A(); P1_ISSUE_A(6);
        VM8(); P1_COMP_B(); P1_ISSUE_B(7);
        VM8(); P1_COMP_A(); P1_ISSUE_A(8);
        VM8(); P1_COMP_B();
        VM0(); P1_COMP_A();
    }
    // partials: pb[((kq*2+nt)*16 + c)*64 + px_local], c = lane&15
    *(f32x4*)&pb[((kq * 2 + 0) * 16 + (lane & 15)) * 64 + (m_sub << 4) + (quad << 2)] = oa0;
    *(f32x4*)&pb[((kq * 2 + 1) * 16 + (lane & 15)) * 64 + (m_sub << 4) + (quad << 2)] = oa1;
    BAR();

    // ===== phase 2: params; om(cg,px) = sum over 4 kq partials =====
    if (tid < 576) {
        const int p2 = tid & 63, tp = tid >> 6;
        const int ky = (tp * 11) >> 5, kx = tp - ky * 3;
#define RD4(cg) (pb[((cg) << 6) + p2] + pb[((cg) << 6) + p2 + 2048] \
               + pb[((cg) << 6) + p2 + 4096] + pb[((cg) << 6) + p2 + 6144])
        const float dyv = RD4(2 * tp) + b_off[2 * tp];
        const float dxv = RD4(2 * tp + 1) + b_off[2 * tp + 1];
        const float mo  = RD4(18 + tp) + b_off[18 + tp];
#undef RD4
        const float mv  = 1.f / (1.f + expf(-mo));
        const float py  = dyv + (float)(h - 1 + ky);
        const float pxf = dxv + (float)(p2 - 1 + kx);
        const float y0f = floorf(py), x0f = floorf(pxf);
        const float wy = py - y0f,    wx = pxf - x0f;
        const float vy0 = (y0f >=  0.f && y0f <= 63.f) ? 1.f : 0.f;
        const float vy1 = (y0f >= -1.f && y0f <= 62.f) ? 1.f : 0.f;
        const int ry0 = (int)fminf(fmaxf(y0f, 0.f), 63.f);
        const int ry1 = (int)fminf(fmaxf(y0f + 1.f, 0.f), 63.f);
        const float rw0 = (1.f - wy) * vy0 * mv;
        const float rw1 = wy * vy1 * mv;
        const bool in01 = (x0f >= 0.f && x0f <= 62.f);
        const float wa = in01 ? (1.f - wx) : ((x0f == -1.f) ? wx : 0.f);
        const float wb = in01 ? wx : ((x0f == 63.f) ? (1.f - wx) : 0.f);
        const int bx = (int)fminf(fmaxf(x0f, 0.f), 62.f);
        pwt[tid]  = make_float4(wa, wb, rw0, rw1);
        pidx[tid] = make_int2(ry0 * 64 + bx, ry1 * 64 + bx);
    }
    BAR();

    // ===== phase 3: asm-pipelined sampling + main GEMM =====
    f32x4 acc0 = {0.f, 0.f, 0.f, 0.f}, acc1 = {0.f, 0.f, 0.f, 0.f};
    f32x4 acc2 = {0.f, 0.f, 0.f, 0.f}, acc3 = {0.f, 0.f, 0.f, 0.f};
    {
        uint4v r0a, r0b, r0c, r0d, r1a, r1b, r1c, r1d;
        short8 bf0r, bf1r, bf2r, bf3r, bf4r, bf5r, bf6r, bf7r;
        VM0();                                        // clean slate (phase-2 loads)
        GA_ISSUE(0);
        VM0();
        WRITE3(0, 0);                                 // overwrites pb (dead now)
        GA_ISSUE(1);
        BF_ISSUE(0);
        BAR();
        R3_MID(0); R3_MID(1); R3_MID(2); R3_MID(3);
        R3_MID(4); R3_MID(5); R3_MID(6);
        // t = 7: no GA(9)
        VM8(); WRITE3(8, 0);
        VM0(); MFMA3(7);
        BF_ISSUE(8);
        BAR();
        // t = 8
        VM0(); MFMA3(8);
    }

    // epilogue: w = m*16 + quad*4 + reg; cout n = wv*16 + (lane&15)
    {
        const int n = (wv << 4) + (lane & 15);
        float* ob = out + (((size_t)((b << 8) + n)) << 12) + (h << 6);
        *(f32x4*)(ob + (quad << 2))      = acc0;
        *(f32x4*)(ob + 16 + (quad << 2)) = acc1;
        *(f32x4*)(ob + 32 + (quad << 2)) = acc2;
        *(f32x4*)(ob + 48 + (quad << 2)) = acc3;
    }
}

// ---- k_fb: direct-fp32 fallback, 512 thr, grid 512 ----
__global__ __launch_bounds__(512, 4) void k_fb(
    const float* __restrict__ x,
    const float* __restrict__ b_off,
    const ushort_t* __restrict__ wfrag,
    float* __restrict__ out)
{
    __shared__ short As[2][32 * 264];
    __shared__ __align__(16) float4 pwt[9 * 32];
    __shared__ __align__(16) int2   pidx[9 * 32];
    float* om_s = (float*)&As[0][0];

    const int bid = blockIdx.x;
    const int sid = ((bid & 7) << 6) | (bid >> 3);
    const int m0  = sid << 5;
    const int b   = m0 >> 12;
    const int h   = (m0 >> 6) & 63;
    const int wbase = m0 & 63;
    const int tid  = threadIdx.x;
    const int lane = tid & 63;
    const int wv   = tid >> 6;
    const int quad = lane >> 4;
    const int px   = tid & 31;
    const int slot = tid >> 5;

    const float*  xb = x + (b << 20);
    const ushort_t* woffb = wfrag + WOFF_FRAG_OFF;

    const int m_w = wv & 1, nt_w = (wv >> 1) & 1;
    f32x4 om_acc = {0.f, 0.f, 0.f, 0.f};
    auto stage1 = [&](int tap, int bufi) {
        const int ky = (tap * 11) >> 5, kx = tap - ky * 3;
        const int yy = h + ky - 1;
        const int xx = wbase + px + kx - 1;
        const bool v = ((unsigned)yy < 64u) & ((unsigned)xx < 64u);
        const int idx = v ? (yy << 6) + xx : 0;
        uint_t lo16[16];
#pragma unroll
        for (int c = 0; c < 16; ++c) {
            const int cin = (slot << 4) + c;
            const float t0 = xb[(cin << 12) + idx];
            lo16[c] = v ? (uint_t)f2bf(t0) : 0u;
        }
        uint_t o[8];
#pragma unroll
        for (int k = 0; k < 8; ++k) o[k] = lo16[2 * k] | (lo16[2 * k + 1] << 16);
        uint_t* dst = (uint_t*)&As[bufi][0] + px * 132 + slot * 8;
        *(uint4*)dst       = make_uint4(o[0], o[1], o[2], o[3]);
        *(uint4*)(dst + 4) = make_uint4(o[4], o[5], o[6], o[7]);
    };
    auto mfma1 = [&](int tap) {
        if (wv < 4) {
            const short* cur = &As[tap & 1][0];
#pragma unroll
            for (int k2 = 0; k2 < 8; ++k2) {
                const int ktg = tap * 8 + k2;
                const short8 a = *(const short8*)&cur[((m_w << 4) + (lane & 15)) * 264 + k2 * 32 + quad * 8];
                const short8 bf = *(const short8*)(woffb + ((ktg * 2 + nt_w) * 64 + lane) * 8);
                om_acc = __builtin_amdgcn_mfma_f32_16x16x32_bf16(a, bf, om_acc, 0, 0, 0);
            }
        }
    };
    stage1(0, 0);
    __syncthreads();
    for (int tap = 0; tap < 9; ++tap) {
        if (tap < 8) stage1(tap + 1, (tap + 1) & 1);
        mfma1(tap);
        __syncthreads();
    }
    if (wv < 4) {
        const int c = (nt_w << 4) + (lane & 15);
        *(f32x4*)&om_s[c * 32 + (m_w << 4) + (quad << 2)] = om_acc;
    }
    __syncthreads();
    if (tid < 288) {
        const int p2 = tid & 31, tp = tid >> 5;
        const int ky = (tp * 11) >> 5, kx = tp - ky * 3;
        const float dyv = om_s[(2 * tp) * 32 + p2] + b_off[2 * tp];
        const float dxv = om_s[(2 * tp + 1) * 32 + p2] + b_off[2 * tp + 1];
        const float mo  = om_s[(18 + tp) * 32 + p2] + b_off[18 + tp];
        const float mv  = 1.f / (1.f + expf(-mo));
        const float py  = dyv + (float)(h - 1 + ky);
        const float pxf = dxv + (float)(wbase + p2 - 1 + kx);
        const float y0f = floorf(py), x0f = floorf(pxf);
        const float wy = py - y0f,    wx = pxf - x0f;
        const float vy0 = (y0f >=  0.f && y0f <= 63.f) ? 1.f : 0.f;
        const float vy1 = (y0f >= -1.f && y0f <= 62.f) ? 1.f : 0.f;
        const int ry0 = (int)fminf(fmaxf(y0f, 0.f), 63.f);
        const int ry1 = (int)fminf(fmaxf(y0f + 1.f, 0.f), 63.f);
        const float rw0 = (1.f - wy) * vy0 * mv;
        const float rw1 = wy * vy1 * mv;
        const bool in01 = (x0f >= 0.f && x0f <= 62.f);
        const float wa = in01 ? (1.f - wx) : ((x0f == -1.f) ? wx : 0.f);
        const float wb = in01 ? wx : ((x0f == 63.f) ? (1.f - wx) : 0.f);
        const int bx = (int)fminf(fmaxf(x0f, 0.f), 62.f);
        pwt[tid]  = make_float4(wa, wb, rw0, rw1);
        pidx[tid] = make_int2(ry0 * 64 + bx, ry1 * 64 + bx);
    }
    __syncthreads();

    f32x4 acc00 = {0.f, 0.f, 0.f, 0.f}, acc01 = {0.f, 0.f, 0.f, 0.f};
    f32x4 acc10 = {0.f, 0.f, 0.f, 0.f}, acc11 = {0.f, 0.f, 0.f, 0.f};
    const int nt_base = wv << 1;
    auto stage3 = [&](int tap, int bufi) {
        const float4 wt = pwt[tap * 32 + px];
        const int2   ii = pidx[tap * 32 + px];
        uint_t o[8];
#pragma unroll
        for (int k = 0; k < 8; ++k) {
            ushort_t s[2];
#pragma unroll
            for (int u = 0; u < 2; ++u) {
                const int cin = (slot << 4) + 2 * k + u;
                const pairf pa = *(const pairf*)(xb + (cin << 12) + ii.x);
                const pairf pb2 = *(const pairf*)(xb + (cin << 12) + ii.y);
                const float v = (pa.x * wt.x + pa.y * wt.y) * wt.z
                              + (pb2.x * wt.x + pb2.y * wt.y) * wt.w;
                s[u] = f2bf(v);
            }
            o[k] = (uint_t)s[0] | ((uint_t)s[1] << 16);
        }
        uint_t* dst = (uint_t*)&As[bufi][0] + px * 132 + slot * 8;
        *(uint4*)dst       = make_uint4(o[0], o[1], o[2], o[3]);
        *(uint4*)(dst + 4) = make_uint4(o[4], o[5], o[6], o[7]);
    };
    auto mfma3 = [&](int tap) {
        const short* cur = &As[tap & 1][0];
#pragma unroll
        for (int k2 = 0; k2 < 8; ++k2) {
            const int ktg = tap * 8 + k2;
            const short8 a0v = *(const short8*)&cur[(lane & 15) * 264 + k2 * 32 + quad * 8];
            const short8 a1v = *(const short8*)&cur[((lane & 15) + 16) * 264 + k2 * 32 + quad * 8];
            const short8 bf0 = *(const short8*)(wfrag + ((ktg * 16 + nt_base) * 64 + lane) * 8);
            const short8 bf1 = *(const short8*)(wfrag + ((ktg * 16 + nt_base + 1) * 64 + lane) * 8);
            acc00 = __builtin_amdgcn_mfma_f32_16x16x32_bf16(a0v, bf0, acc00, 0, 0, 0);
            acc01 = __builtin_amdgcn_mfma_f32_16x16x32_bf16(a0v, bf1, acc01, 0, 0, 0);
            acc10 = __builtin_amdgcn_mfma_f32_16x16x32_bf16(a1v, bf0, acc10, 0, 0, 0);
            acc11 = __builtin_amdgcn_mfma_f32_16x16x32_bf16(a1v, bf1, acc11, 0, 0, 0);
        }
    };
    stage3(0, 0);
    __syncthreads();
    for (int tap = 0; tap < 9; ++tap) {
        if (tap < 8) stage3(tap + 1, (tap + 1) & 1);
        mfma3(tap);
        __syncthreads();
    }
    {
        const int w0 = wbase + (quad << 2);
        const int w1 = wbase + 16 + (quad << 2);
        const int n0 = (wv << 5) + (lane & 15);
        const int n1 = (wv << 5) + 16 + (lane & 15);
        *(f32x4*)(out + (((size_t)((b << 8) + n0)) << 12) + (h << 6) + w0) = acc00;
        *(f32x4*)(out + (((size_t)((b << 8) + n1)) << 12) + (h << 6) + w0) = acc01;
        *(f32x4*)(out + (((size_t)((b << 8) + n0)) << 12) + (h << 6) + w1) = acc10;
        *(f32x4*)(out + (((size_t)((b << 8) + n1)) << 12) + (h << 6) + w1) = acc11;
    }
}

extern "C" void kernel_launch(void* const* d_in, const int* in_sizes, int n_in,
                              void* d_out, int out_size, void* d_ws, size_t ws_size,
                              hipStream_t stream) {
    const float* x      = (const float*)d_in[0];
    const float* w_off  = (const float*)d_in[1];
    const float* b_off  = (const float*)d_in[2];
    const float* w_conv = (const float*)d_in[3];
    float* out = (float*)d_out;

    const size_t need1 = XPAIR_BYTES + WFRAG_BYTES;   // 18,104,320
    const int mode = (ws_size >= need1) ? 1 : 0;

    uint_t*   xpair = (uint_t*)d_ws;
    ushort_t* wfrag = (mode >= 1) ? (ushort_t*)((char*)d_ws + XPAIR_BYTES)
                                  : (ushort_t*)d_ws;
    const int XB = (mode >= 1) ? 512 : 0;

    hipLaunchKernelGGL(k_pre, dim3(XB + 162), dim3(512), 0, stream,
                       x, w_conv, w_off, wfrag, xpair, XB);
    if (mode == 1)
        hipLaunchKernelGGL(k_main, dim3(256), dim3(1024), 0, stream,
                           xpair, b_off, wfrag, out);
    else
        hipLaunchKernelGGL(k_fb, dim3(512), dim3(512), 0, stream,
                           x, b_off, wfrag, out);
}